// Round 16
// baseline (144.330 us; speedup 1.0000x reference)
//
#include <hip/hip_runtime.h>
#include <hip/hip_bf16.h>
#include <math.h>

typedef __hip_bfloat16 bf16;
typedef __attribute__((ext_vector_type(8))) short short8;
typedef __attribute__((ext_vector_type(4))) short short4v;
typedef __attribute__((ext_vector_type(4))) float floatx4;

__device__ __forceinline__ bf16 f2b(float v) { return __float2bfloat16(v); }
__device__ __forceinline__ short f2s(float v) {
    bf16 h = __float2bfloat16(v);
    return *reinterpret_cast<short*>(&h);
}
__device__ __forceinline__ float s2f(short s) {
    union { unsigned u; float f; } t;
    t.u = ((unsigned)(unsigned short)s) << 16;
    return t.f;
}
__device__ __forceinline__ float gelu_exact(float x) {
    return 0.5f * x * (1.0f + erff(x * 0.70710678118654752440f));
}
__device__ __forceinline__ float sigmoidf_(float x) {
    return 1.0f / (1.0f + __expf(-x));
}
__device__ __forceinline__ float ldin(const void* p, int i, bool isbf) {
    return isbf ? s2f(((const short*)p)[i]) : ((const float*)p)[i];
}
#define MFMA16(a, b, c) __builtin_amdgcn_mfma_f32_16x16x32_bf16(a, b, c, 0, 0, 0)

// fp32 params block layout (offsets in floats)
#define P_DWK    0
#define P_DWB    2304
#define P_DWG    2560
#define P_DWBT   2816
#define P_DWM    3072
#define P_DWV    3328
#define P_CIW1   3584
#define P_CIB1   11776
#define P_CIG    11808
#define P_CIBT   11840
#define P_CIM    11872
#define P_CIV    11904
#define P_CIW2   11936
#define P_CIB2   20128
#define P_SIW1   20384
#define P_SIB1   24480
#define P_SIG    24496
#define P_SIBT   24512
#define P_SIM    24528
#define P_SIV    24544
#define P_SIW2   24560
#define P_SIB2   24576
#define P_TEMP   24577
#define P_BPROJ  24585

// ---------------------------------------------------------------------------
// helper: per-block dtype sniff of x's first 4096 words (L2-hot, ~1us total).
// ---------------------------------------------------------------------------
__device__ __forceinline__ bool block_sniff(const unsigned* __restrict__ x) {
    int cnt = 0;
    for (int i = threadIdx.x; i < 4096; i += 256) {
        unsigned lo = x[i] & 0xFFFFu;
        unsigned e = (lo >> 7) & 0xFFu;
        cnt += (e >= 0x66u && e <= 0x8Au) ? 1 : 0;
    }
    __shared__ int red[256];
    red[threadIdx.x] = cnt;
    __syncthreads();
    for (int o = 128; o > 0; o >>= 1) {
        if (threadIdx.x < o) red[threadIdx.x] += red[threadIdx.x + o];
        __syncthreads();
    }
    return red[0] > 2048;
}

// ---------------------------------------------------------------------------
// K_prept (node 1): merged prep + transposes (every block self-sniffs dtype).
// ---------------------------------------------------------------------------
struct CvtArgs { const void* src[24]; int dst[24]; int cnt[24]; };

__global__ __launch_bounds__(256) void k_prept(CvtArgs a,
                                               const void* __restrict__ x,
                                               const void* __restrict__ wqkv,
                                               const void* __restrict__ wproj,
                                               bf16* __restrict__ xT,
                                               bf16* __restrict__ wqkvT,
                                               bf16* __restrict__ wprojT,
                                               float* __restrict__ prm,
                                               unsigned* __restrict__ flag,
                                               float* __restrict__ accbuf) {
    __shared__ short T[64][72];
    const bool isbf = block_sniff((const unsigned*)x);
    const int id = blockIdx.x;
    const int tid = threadIdx.x;

    if (id >= 2112) {
        int e = id - 2112;
        if (e < 24) {
            const void* s = a.src[e];
            float* d = prm + a.dst[e];
            const int n = a.cnt[e];
            for (int i = tid; i < n; i += 256) d[i] = ldin(s, i, isbf);
        } else {
            for (int i = tid; i < 6144; i += 256) accbuf[i] = 0.f;
            if (tid == 0) *flag = isbf ? 1u : 0u;
        }
        return;
    }

    const int cc = tid >> 3, oct = tid & 7;
    const void* src;
    bf16* dst;
    long row_stride, src_off;
    int c0;
    long out_row_off;
    if (id < 2048) {
        int nx = id & 63, cy = (id >> 6) & 3, b = id >> 8;
        c0 = cy * 64;
        int n0 = nx * 64;
        src = x;
        dst = xT;
        row_stride = 4096;
        src_off = ((long)(b * 256 + c0) << 12) + n0;
        out_row_off = ((long)(b << 12) + n0) << 8;
    } else if (id < 2096) {
        int id2 = id - 2048;
        int jx = id2 % 12, cy = id2 / 12;
        c0 = cy * 64;
        int j0 = jx * 64;
        src = wqkv;
        dst = wqkvT;
        row_stride = 768;
        src_off = (long)c0 * 768 + j0;
        out_row_off = (long)j0 << 8;
    } else {
        int id3 = id - 2096;
        int jx = id3 & 3, cy = id3 >> 2;
        c0 = cy * 64;
        int j0 = jx * 64;
        src = wproj;
        dst = wprojT;
        row_stride = 256;
        src_off = (long)c0 * 256 + j0;
        out_row_off = (long)j0 << 8;
    }

#pragma unroll
    for (int i = 0; i < 2; ++i) {
        int col = cc + i * 32;
        long gbase = src_off + (long)col * row_stride + oct * 8;
        short v[8];
        if (isbf) {
            short8 p = *(const short8*)((const short*)src + gbase);
#pragma unroll
            for (int u = 0; u < 8; ++u) v[u] = p[u];
        } else {
            floatx4 q0 = *(const floatx4*)((const float*)src + gbase);
            floatx4 q1 = *(const floatx4*)((const float*)src + gbase + 4);
#pragma unroll
            for (int u = 0; u < 4; ++u) { v[u] = f2s(q0[u]); v[4 + u] = f2s(q1[u]); }
        }
        int row0 = oct * 8;
#pragma unroll
        for (int u = 0; u < 8; ++u) {
            int row = row0 + u;
            T[row][(((col >> 3) ^ (row & 7)) << 3) + (col & 7)] = v[u];
        }
    }
    __syncthreads();
    const int rr = tid >> 3;
#pragma unroll
    for (int i = 0; i < 2; ++i) {
        int row = rr + i * 32;
        short8 p = *(const short8*)&T[row][((oct ^ (row & 7)) << 3)];
        *(short8*)&dst[out_row_off + ((long)row << 8) + c0 + oct * 8] = p;
    }
}

// ---------------------------------------------------------------------------
// K1 (node 2): qkv GEMM (MFMA), 128x128 tile, 4 waves (64x64 quadrants).
// ---------------------------------------------------------------------------
__global__ __launch_bounds__(256) void k_qkv_m3(const bf16* __restrict__ xT,
                                                const bf16* __restrict__ wT,
                                                bf16* __restrict__ qb,
                                                bf16* __restrict__ kb,
                                                bf16* __restrict__ vbb,
                                                float* __restrict__ qss,
                                                float* __restrict__ kss) {
    __shared__ short As[128][72];
    __shared__ short Bs[128][72];
    const int id = blockIdx.x;                 // 1536 = 8 * 192
    const int swz = (id & 7) * 192 + (id >> 3);
    const int y = swz % 6;
    const int rest = swz / 6;
    const int n0 = (rest & 31) * 128;
    const int b = rest >> 5;
    const int j0 = y * 128;
    const int tid = threadIdx.x;
    const int wid = tid >> 6, l = tid & 63;
    const int wr = wid >> 1, wc = wid & 1;
    const int lm = l & 15, lk = (l >> 4) * 8;
    const int srow = tid >> 3, soct = tid & 7;
    floatx4 acc[4][4];
#pragma unroll
    for (int i = 0; i < 4; ++i)
#pragma unroll
        for (int j = 0; j < 4; ++j) acc[i][j] = (floatx4){0.f, 0.f, 0.f, 0.f};

    for (int k0 = 0; k0 < 256; k0 += 64) {
        __syncthreads();
#pragma unroll
        for (int i = 0; i < 4; ++i) {
            int row = srow + i * 32;
            *(short8*)&As[row][soct * 8] =
                *(const short8*)&wT[((j0 + row) << 8) + k0 + soct * 8];
            *(short8*)&Bs[row][soct * 8] =
                *(const short8*)&xT[(((b << 12) + n0 + row) << 8) + k0 + soct * 8];
        }
        __syncthreads();
#pragma unroll
        for (int h = 0; h < 2; ++h) {
            short8 af[4], bfv[4];
#pragma unroll
            for (int mt = 0; mt < 4; ++mt)
                af[mt] = *(const short8*)&As[wr * 64 + mt * 16 + lm][h * 32 + lk];
#pragma unroll
            for (int nt = 0; nt < 4; ++nt)
                bfv[nt] = *(const short8*)&Bs[wc * 64 + nt * 16 + lm][h * 32 + lk];
#pragma unroll
            for (int mt = 0; mt < 4; ++mt)
#pragma unroll
                for (int nt = 0; nt < 4; ++nt)
                    acc[mt][nt] = MFMA16(af[mt], bfv[nt], acc[mt][nt]);
        }
    }
    const int jbase = wr * 64 + (l >> 4) * 4;
    const int jq = (y & 1) * 128;
    if (y < 4) {
        bf16* dst = (y < 2) ? qb : kb;
#pragma unroll
        for (int mt = 0; mt < 4; ++mt)
#pragma unroll
            for (int nt = 0; nt < 4; ++nt) {
                int n = n0 + wc * 64 + nt * 16 + lm;
#pragma unroll
                for (int r = 0; r < 4; ++r)
                    dst[(((b << 8) + jq + jbase + mt * 16 + r) << 12) + n] =
                        f2b(acc[mt][nt][r]);
            }
        __syncthreads();
        float* red = (float*)&As[0][0];
#pragma unroll
        for (int mt = 0; mt < 4; ++mt)
#pragma unroll
            for (int r = 0; r < 4; ++r) {
                float s = 0.f;
#pragma unroll
                for (int nt = 0; nt < 4; ++nt) {
                    float v = acc[mt][nt][r];
                    s = fmaf(v, v, s);
                }
                red[(jbase + mt * 16 + r) * 32 + wc * 16 + lm] = s;
            }
        __syncthreads();
        if (tid < 128) {
            float s = 0.f;
#pragma unroll
            for (int i = 0; i < 32; ++i)
                s += red[tid * 32 + ((i + tid) & 31)];
            float* dsts = (y < 2) ? qss : kss;
            atomicAdd(&dsts[(b << 8) + jq + tid], s);
        }
    } else {
#pragma unroll
        for (int mt = 0; mt < 4; ++mt)
#pragma unroll
            for (int nt = 0; nt < 4; ++nt) {
                int n = n0 + wc * 64 + nt * 16 + lm;
#pragma unroll
                for (int r = 0; r < 4; ++r)
                    vbb[(((b << 8) + jq + jbase + mt * 16 + r) << 12) + n] =
                        f2b(acc[mt][nt][r]);
            }
    }
}

// ---------------------------------------------------------------------------
// K_qkdw (node 3): id<64 -> fused QK^T+softmax; id>=64 -> dwconv+BN+GELU+T.
// ---------------------------------------------------------------------------
__global__ __launch_bounds__(256) void k_qkdw(const bf16* __restrict__ qb,
                                              const bf16* __restrict__ kb,
                                              const float* __restrict__ qss,
                                              const float* __restrict__ kss,
                                              const bf16* __restrict__ vbb,
                                              const float* __restrict__ prm,
                                              float* __restrict__ attn,
                                              bf16* __restrict__ convT) {
    __shared__ __align__(16) char smem[38368];
    const int id = blockIdx.x;
    const int tid = threadIdx.x;
    if (id < 64) {
        float (*AS)[32] = (float(*)[32])smem;
        const int h = id & 7, b = id >> 3;
        const int wid = tid >> 6, l = tid & 63;
        const int lm = l & 15, lk = (l >> 4) * 8;
        floatx4 acc[2][2];
#pragma unroll
        for (int i = 0; i < 2; ++i)
#pragma unroll
            for (int j = 0; j < 2; ++j) acc[i][j] = (floatx4){0.f, 0.f, 0.f, 0.f};
        const int cbase = (b << 8) + h * 32;
        for (int it = 0; it < 32; ++it) {
            int n = wid * 1024 + it * 32 + lk;
            short8 a0 = *(const short8*)&qb[((cbase + lm) << 12) + n];
            short8 a1 = *(const short8*)&qb[((cbase + 16 + lm) << 12) + n];
            short8 b0 = *(const short8*)&kb[((cbase + lm) << 12) + n];
            short8 b1 = *(const short8*)&kb[((cbase + 16 + lm) << 12) + n];
            acc[0][0] = MFMA16(a0, b0, acc[0][0]);
            acc[0][1] = MFMA16(a0, b1, acc[0][1]);
            acc[1][0] = MFMA16(a1, b0, acc[1][0]);
            acc[1][1] = MFMA16(a1, b1, acc[1][1]);
        }
        for (int i = tid; i < 1024; i += 256) ((float*)AS)[i] = 0.f;
        __syncthreads();
#pragma unroll
        for (int mt = 0; mt < 2; ++mt)
#pragma unroll
            for (int nt = 0; nt < 2; ++nt)
#pragma unroll
                for (int r = 0; r < 4; ++r)
                    atomicAdd(&AS[mt * 16 + (l >> 4) * 4 + r][nt * 16 + lm],
                              acc[mt][nt][r]);
        __syncthreads();
        if (tid < 32) {
            const int c = tid;
            float qsc = rsqrtf(fmaxf(qss[cbase + c], 1e-12f)) * prm[P_TEMP + h];
            float row[32];
            float m = -1e30f;
#pragma unroll
            for (int d = 0; d < 32; ++d) {
                row[d] = AS[c][d] * qsc * rsqrtf(fmaxf(kss[cbase + d], 1e-12f));
                m = fmaxf(m, row[d]);
            }
            float s = 0.f;
#pragma unroll
            for (int d = 0; d < 32; ++d) {
                row[d] = __expf(row[d] - m);
                s += row[d];
            }
            float inv = 1.0f / s;
            float* dst = attn + ((b * 8 + h) << 10) + c * 32;
#pragma unroll
            for (int d = 0; d < 32; ++d) dst[d] = row[d] * inv;
        }
    } else {
        float (*S)[18][66] = (float(*)[18][66])smem;
        float (*Wl)[11] = (float(*)[11])(smem + 38016);
        const int id2 = id - 64;
        const int y0 = (id2 & 3) * 16, c0 = ((id2 >> 2) & 31) * 8, b = id2 >> 7;
        if (tid < 144) {
            int ch = tid / 18, r = tid - ch * 18;
            int gy = y0 + r - 1;
            float* drow = &S[ch][r][0];
            if (gy < 0 || gy > 63) {
                for (int i = 0; i < 66; ++i) drow[i] = 0.f;
            } else {
                const short* src = (const short*)vbb +
                                   ((((b << 8) + c0 + ch) << 12) + gy * 64);
                drow[0] = 0.f;
                drow[65] = 0.f;
#pragma unroll
                for (int g = 0; g < 8; ++g) {
                    short8 p = *(const short8*)(src + g * 8);
#pragma unroll
                    for (int u = 0; u < 8; ++u) drow[1 + g * 8 + u] = s2f(p[u]);
                }
            }
        } else if (tid >= 248) {
            int ch = tid - 248;
            int c = c0 + ch;
            float scale = rsqrtf(prm[P_DWV + c] + 1e-3f) * prm[P_DWG + c];
#pragma unroll
            for (int e = 0; e < 9; ++e) Wl[ch][e] = prm[P_DWK + c * 9 + e] * scale;
            Wl[ch][10] = (prm[P_DWB + c] - prm[P_DWM + c]) * scale + prm[P_DWBT + c];
        }
        __syncthreads();
        const int row = tid >> 4, xl = tid & 15;
#pragma unroll
        for (int u = 0; u < 4; ++u) {
            int x = xl + u * 16;
            short8 o;
#pragma unroll
            for (int ch = 0; ch < 8; ++ch) {
                float acc = Wl[ch][10];
#pragma unroll
                for (int ky = 0; ky < 3; ++ky)
#pragma unroll
                    for (int kx = 0; kx < 3; ++kx)
                        acc = fmaf(S[ch][row + ky][x + kx], Wl[ch][ky * 3 + kx], acc);
                o[ch] = f2s(gelu_exact(acc));
            }
            *(short8*)&((short*)convT)[(((b << 12) + (y0 + row) * 64 + x) << 8) + c0] = o;
        }
    }
}

// ---------------------------------------------------------------------------
// K_attv_sm (node 4): id<1024 -> att = attn @ v -> attT + gap atomics;
// id>=1024 -> spatial gate sigsm from convT.
// ROUND-16: LDS reads vectorized to b128 (A row: 8x floatx4; W1 row: 4x
// floatx4) — cuts per-thread LDS instruction count 4x (issue-bound fix).
// ---------------------------------------------------------------------------
__global__ __launch_bounds__(256) void k_attv_sm(const float* __restrict__ attn,
                                                 const bf16* __restrict__ vbb,
                                                 const bf16* __restrict__ convT,
                                                 const float* __restrict__ prm,
                                                 bf16* __restrict__ attT,
                                                 float* __restrict__ gap,
                                                 float* __restrict__ sigsm) {
    __shared__ __align__(16) char smem[36864];
    const int id = blockIdx.x;
    const int tid = threadIdx.x;
    if (id < 1024) {
        float (*A)[32] = (float(*)[32])smem;
        float (*G)[32] = (float(*)[32])(smem + 4096);
        const int nx = id & 15, h = (id >> 4) & 7, b = id >> 7;
        const int n = nx * 256 + tid;
        for (int i = tid; i < 1024; i += 256)
            ((float*)A)[i] = attn[((b * 8 + h) << 10) + i];
        __syncthreads();
        const int base = ((b * 256 + h * 32) << 12) + n;
        float vv[32];
#pragma unroll
        for (int d = 0; d < 32; ++d) vv[d] = s2f(((const short*)vbb)[base + (d << 12)]);
        float av[32];
#pragma unroll
        for (int c = 0; c < 32; ++c) {
            const floatx4* ar = (const floatx4*)&A[c][0];
            float s = 0.f;
#pragma unroll
            for (int d4 = 0; d4 < 8; ++d4) {
                floatx4 a4 = ar[d4];                 // ds_read_b128 broadcast
#pragma unroll
                for (int u = 0; u < 4; ++u)
                    s = fmaf(a4[u], vv[d4 * 4 + u], s);
            }
            av[c] = s;
            G[tid][(c + tid) & 31] = s;              // rotated: conflict-free
        }
        const int obase = (((b << 12) + n) << 8) + h * 32;
#pragma unroll
        for (int g = 0; g < 4; ++g) {
            short8 p;
#pragma unroll
            for (int u = 0; u < 8; ++u) p[u] = f2s(av[g * 8 + u]);
            *(short8*)&attT[obase + g * 8] = p;
        }
        __syncthreads();
        {
            const int colc = tid & 31, rg = tid >> 5;
            float s = 0.f;
#pragma unroll
            for (int i = 0; i < 32; ++i) {
                int row = rg * 32 + i;
                s += G[row][(colc + row) & 31];      // inverse rotation
            }
            A[rg][colc] = s;
        }
        __syncthreads();
        if (tid < 32) {
            float s = 0.f;
#pragma unroll
            for (int g = 0; g < 8; ++g) s += A[g][tid];
            atomicAdd(&gap[(b << 8) + h * 32 + tid], s);
        }
    } else {
        float (*W1)[16] = (float(*)[16])smem;
        const int id2 = id - 1024;
        const int nx = id2 & 15, b = id2 >> 4;
        const int n = nx * 256 + tid;
        for (int i = tid; i < 4096; i += 256) W1[i >> 4][i & 15] = prm[P_SIW1 + i];
        __syncthreads();
        floatx4 acc4[4];
#pragma unroll
        for (int q = 0; q < 4; ++q) acc4[q] = (floatx4){0.f, 0.f, 0.f, 0.f};
        const bf16* src = convT + (((b << 12) + n) << 8);
#pragma unroll 4
        for (int g = 0; g < 32; ++g) {
            short8 p = *(const short8*)&src[g * 8];
#pragma unroll
            for (int u = 0; u < 8; ++u) {
                float v = s2f(p[u]);
                const floatx4* wr = (const floatx4*)&W1[g * 8 + u][0];
#pragma unroll
                for (int q = 0; q < 4; ++q) {
                    floatx4 w4 = wr[q];              // ds_read_b128 broadcast
#pragma unroll
                    for (int e = 0; e < 4; ++e)
                        acc4[q][e] = fmaf(v, w4[e], acc4[q][e]);
                }
            }
        }
        float sm = prm[P_SIB2];
#pragma unroll
        for (int o = 0; o < 16; ++o) {
            float t = acc4[o >> 2][o & 3] + prm[P_SIB1 + o];
            t = (t - prm[P_SIM + o]) * rsqrtf(prm[P_SIV + o] + 1e-3f) * prm[P_SIG + o] +
                prm[P_SIBT + o];
            sm = fmaf(gelu_exact(t), prm[P_SIW2 + o], sm);
        }
        sigsm[(b << 12) + n] = sigmoidf_(sm);
    }
}

// ---------------------------------------------------------------------------
// K9 (node 5): final projection (MFMA), 128x128 tile; inline channel gate.
// ---------------------------------------------------------------------------
__global__ __launch_bounds__(256) void k_proj_m3(const bf16* __restrict__ attT,
                                                 const bf16* __restrict__ convT,
                                                 const float* __restrict__ sigsm,
                                                 const float* __restrict__ gap,
                                                 const bf16* __restrict__ wpT,
                                                 const float* __restrict__ prm,
                                                 const unsigned* __restrict__ flag,
                                                 void* __restrict__ out) {
    __shared__ short As[128][72];
    __shared__ short Bs[128][72];
    __shared__ float scs[256];
    const bool isbf = (*flag != 0u);
    const int id = blockIdx.x;                 // 512 = 8 * 64
    const int swz = (id & 7) * 64 + (id >> 3);
    const int j0 = (swz & 1) * 128;
    const int rest = swz >> 1;
    const int n0 = (rest & 31) * 128;
    const int b = rest >> 5;
    const int tid = threadIdx.x;
    const int wid = tid >> 6, l = tid & 63;
    const int wr = wid >> 1, wc = wid & 1;
    const int lm = l & 15, lk = (l >> 4) * 8;
    const int srow = tid >> 3, soct = tid & 7;

    {
        float* gl = (float*)&As[0][0];
        float* rd = gl + 256;
        float* t1 = rd + 256;
        gl[tid] = gap[(b << 8) + tid] * (1.0f / 4096.0f);
        __syncthreads();
        const int o = tid >> 3, g = tid & 7;
        float s1 = 0.f;
#pragma unroll
        for (int i = 0; i < 32; ++i) {
            int c = g * 32 + i;
            s1 = fmaf(gl[c], prm[P_CIW1 + c * 32 + o], s1);
        }
        rd[o * 8 + g] = s1;
        __syncthreads();
        if (tid < 32) {
            float s = prm[P_CIB1 + tid];
#pragma unroll
            for (int g2 = 0; g2 < 8; ++g2) s += rd[tid * 8 + g2];
            s = (s - prm[P_CIM + tid]) * rsqrtf(prm[P_CIV + tid] + 1e-3f) *
                    prm[P_CIG + tid] + prm[P_CIBT + tid];
            t1[tid] = gelu_exact(s);
        }
        __syncthreads();
        float s = prm[P_CIB2 + tid];
#pragma unroll
        for (int o2 = 0; o2 < 32; ++o2)
            s = fmaf(t1[o2], prm[P_CIW2 + o2 * 256 + tid], s);
        scs[tid] = sigmoidf_(s);
    }

    floatx4 acc[4][4];
#pragma unroll
    for (int i = 0; i < 4; ++i)
#pragma unroll
        for (int j = 0; j < 4; ++j) acc[i][j] = (floatx4){0.f, 0.f, 0.f, 0.f};

    for (int k0 = 0; k0 < 256; k0 += 64) {
        __syncthreads();
#pragma unroll
        for (int i = 0; i < 4; ++i) {
            int row = srow + i * 32;
            *(short8*)&As[row][soct * 8] =
                *(const short8*)&wpT[((j0 + row) << 8) + k0 + soct * 8];
            int rbase = (((b << 12) + n0 + row) << 8) + k0 + soct * 8;
            short8 pa = *(const short8*)&attT[rbase];
            short8 pc = *(const short8*)&convT[rbase];
            float sv = sigsm[(b << 12) + n0 + row];
            short8 pz;
#pragma unroll
            for (int u = 0; u < 8; ++u)
                pz[u] = f2s(s2f(pa[u]) * sv + s2f(pc[u]) * scs[k0 + soct * 8 + u]);
            *(short8*)&Bs[row][soct * 8] = pz;
        }
        __syncthreads();
#pragma unroll
        for (int h = 0; h < 2; ++h) {
            short8 af[4], bfv[4];
#pragma unroll
            for (int mt = 0; mt < 4; ++mt)
                af[mt] = *(const short8*)&As[wr * 64 + mt * 16 + lm][h * 32 + lk];
#pragma unroll
            for (int nt = 0; nt < 4; ++nt)
                bfv[nt] = *(const short8*)&Bs[wc * 64 + nt * 16 + lm][h * 32 + lk];
#pragma unroll
            for (int mt = 0; mt < 4; ++mt)
#pragma unroll
                for (int nt = 0; nt < 4; ++nt)
                    acc[mt][nt] = MFMA16(af[mt], bfv[nt], acc[mt][nt]);
        }
    }
    const int jbase = j0 + wr * 64 + (l >> 4) * 4;
#pragma unroll
    for (int mt = 0; mt < 4; ++mt) {
        float bp[4];
#pragma unroll
        for (int r = 0; r < 4; ++r) bp[r] = prm[P_BPROJ + jbase + mt * 16 + r];
#pragma unroll
        for (int nt = 0; nt < 4; ++nt) {
            int n = n0 + wc * 64 + nt * 16 + lm;
#pragma unroll
            for (int r = 0; r < 4; ++r) {
                int idx = (((b << 8) + jbase + mt * 16 + r) << 12) + n;
                float val = acc[mt][nt][r] + bp[r];
                if (isbf) ((bf16*)out)[idx] = f2b(val);
                else ((float*)out)[idx] = val;
            }
        }
    }
}

// ---------------------------------------------------------------------------
extern "C" void kernel_launch(void* const* d_in, const int* in_sizes, int n_in,
                              void* d_out, int out_size, void* d_ws, size_t ws_size,
                              hipStream_t stream) {
    char* ws = (char*)d_ws;
    bf16*  vbb    = (bf16*) (ws);
    bf16*  xT     = (bf16*) (ws + 33554432);
    bf16*  attT   = (bf16*) (ws + 33554432);   // alias xT (dead after qkv)
    bf16*  qb     = (bf16*) (ws + 50331648);
    bf16*  kb     = (bf16*) (ws + 67108864);
    bf16*  wqkvT  = (bf16*) (ws + 83886080);
    bf16*  wprojT = (bf16*) (ws + 84279296);
    float* attn   = (float*)(ws + 84410368);
    float* qss    = (float*)(ws + 85721088);   // qss|kss|gap contiguous 24576B
    float* kss    = (float*)(ws + 85729280);
    float* gap    = (float*)(ws + 85737472);
    float* sigsm  = (float*)(ws + 85753856);
    float* prm    = (float*)(ws + 85884928);
    unsigned* flag = (unsigned*)(ws + 85985280);
    bf16*  convT  = (bf16*) (ws + 100663296);  // 96M, no alias

    CvtArgs a;
    const int map_src[24] = {3, 4, 5, 6, 7, 8, 9, 10, 11, 12, 13, 14, 15, 16, 17,
                             18, 19, 20, 21, 22, 23, 24, 25, 26};
    const int map_dst[24] = {P_BPROJ, P_DWK, P_DWB, P_DWG, P_DWBT, P_DWM, P_DWV,
                             P_CIG, P_CIBT, P_CIM, P_CIV, P_SIG, P_SIBT, P_SIM, P_SIV,
                             P_CIW1, P_CIB1, P_CIW2, P_CIB2, P_SIW1, P_SIB1, P_SIW2,
                             P_SIB2, P_TEMP};
    for (int i = 0; i < 24; ++i) {
        a.src[i] = d_in[map_src[i]];
        a.dst[i] = map_dst[i];
        a.cnt[i] = in_sizes[map_src[i]];
    }

    k_prept<<<2137, 256, 0, stream>>>(a, d_in[0], d_in[1], d_in[2],
                                      xT, wqkvT, wprojT, prm, flag, qss);
    k_qkv_m3<<<1536, 256, 0, stream>>>(xT, wqkvT, qb, kb, vbb, qss, kss);
    k_qkdw<<<1088, 256, 0, stream>>>(qb, kb, qss, kss, vbb, prm, attn, convT);
    k_attv_sm<<<1152, 256, 0, stream>>>(attn, vbb, convT, prm, attT, gap, sigsm);
    k_proj_m3<<<512, 256, 0, stream>>>(attT, convT, sigsm, gap,
                                       wprojT, prm, flag, d_out);
}

// Round 17
// 134.261 us; speedup vs baseline: 1.0750x; 1.0750x over previous
//
#include <hip/hip_runtime.h>
#include <hip/hip_bf16.h>
#include <math.h>

typedef __hip_bfloat16 bf16;
typedef __attribute__((ext_vector_type(8))) short short8;
typedef __attribute__((ext_vector_type(4))) short short4v;
typedef __attribute__((ext_vector_type(4))) float floatx4;

__device__ __forceinline__ bf16 f2b(float v) { return __float2bfloat16(v); }
__device__ __forceinline__ short f2s(float v) {
    bf16 h = __float2bfloat16(v);
    return *reinterpret_cast<short*>(&h);
}
__device__ __forceinline__ float s2f(short s) {
    union { unsigned u; float f; } t;
    t.u = ((unsigned)(unsigned short)s) << 16;
    return t.f;
}
__device__ __forceinline__ float gelu_exact(float x) {
    return 0.5f * x * (1.0f + erff(x * 0.70710678118654752440f));
}
__device__ __forceinline__ float sigmoidf_(float x) {
    return 1.0f / (1.0f + __expf(-x));
}
__device__ __forceinline__ float ldin(const void* p, int i, bool isbf) {
    return isbf ? s2f(((const short*)p)[i]) : ((const float*)p)[i];
}
#define MFMA16(a, b, c) __builtin_amdgcn_mfma_f32_16x16x32_bf16(a, b, c, 0, 0, 0)

// fp32 params block layout (offsets in floats)
#define P_DWK    0
#define P_DWB    2304
#define P_DWG    2560
#define P_DWBT   2816
#define P_DWM    3072
#define P_DWV    3328
#define P_CIW1   3584
#define P_CIB1   11776
#define P_CIG    11808
#define P_CIBT   11840
#define P_CIM    11872
#define P_CIV    11904
#define P_CIW2   11936
#define P_CIB2   20128
#define P_SIW1   20384
#define P_SIB1   24480
#define P_SIG    24496
#define P_SIBT   24512
#define P_SIM    24528
#define P_SIV    24544
#define P_SIW2   24560
#define P_SIB2   24576
#define P_TEMP   24577
#define P_BPROJ  24585

// ---------------------------------------------------------------------------
// helper: per-block dtype sniff of x's first 4096 words (L2-hot, ~1us total).
// ---------------------------------------------------------------------------
__device__ __forceinline__ bool block_sniff(const unsigned* __restrict__ x) {
    int cnt = 0;
    for (int i = threadIdx.x; i < 4096; i += 256) {
        unsigned lo = x[i] & 0xFFFFu;
        unsigned e = (lo >> 7) & 0xFFu;
        cnt += (e >= 0x66u && e <= 0x8Au) ? 1 : 0;
    }
    __shared__ int red[256];
    red[threadIdx.x] = cnt;
    __syncthreads();
    for (int o = 128; o > 0; o >>= 1) {
        if (threadIdx.x < o) red[threadIdx.x] += red[threadIdx.x + o];
        __syncthreads();
    }
    return red[0] > 2048;
}

// ---------------------------------------------------------------------------
// K_prept (node 1): merged prep + transposes (every block self-sniffs dtype).
// ---------------------------------------------------------------------------
struct CvtArgs { const void* src[24]; int dst[24]; int cnt[24]; };

__global__ __launch_bounds__(256) void k_prept(CvtArgs a,
                                               const void* __restrict__ x,
                                               const void* __restrict__ wqkv,
                                               const void* __restrict__ wproj,
                                               bf16* __restrict__ xT,
                                               bf16* __restrict__ wqkvT,
                                               bf16* __restrict__ wprojT,
                                               float* __restrict__ prm,
                                               unsigned* __restrict__ flag,
                                               float* __restrict__ accbuf) {
    __shared__ short T[64][72];
    const bool isbf = block_sniff((const unsigned*)x);
    const int id = blockIdx.x;
    const int tid = threadIdx.x;

    if (id >= 2112) {
        int e = id - 2112;
        if (e < 24) {
            const void* s = a.src[e];
            float* d = prm + a.dst[e];
            const int n = a.cnt[e];
            for (int i = tid; i < n; i += 256) d[i] = ldin(s, i, isbf);
        } else {
            for (int i = tid; i < 6144; i += 256) accbuf[i] = 0.f;
            if (tid == 0) *flag = isbf ? 1u : 0u;
        }
        return;
    }

    const int cc = tid >> 3, oct = tid & 7;
    const void* src;
    bf16* dst;
    long row_stride, src_off;
    int c0;
    long out_row_off;
    if (id < 2048) {
        int nx = id & 63, cy = (id >> 6) & 3, b = id >> 8;
        c0 = cy * 64;
        int n0 = nx * 64;
        src = x;
        dst = xT;
        row_stride = 4096;
        src_off = ((long)(b * 256 + c0) << 12) + n0;
        out_row_off = ((long)(b << 12) + n0) << 8;
    } else if (id < 2096) {
        int id2 = id - 2048;
        int jx = id2 % 12, cy = id2 / 12;
        c0 = cy * 64;
        int j0 = jx * 64;
        src = wqkv;
        dst = wqkvT;
        row_stride = 768;
        src_off = (long)c0 * 768 + j0;
        out_row_off = (long)j0 << 8;
    } else {
        int id3 = id - 2096;
        int jx = id3 & 3, cy = id3 >> 2;
        c0 = cy * 64;
        int j0 = jx * 64;
        src = wproj;
        dst = wprojT;
        row_stride = 256;
        src_off = (long)c0 * 256 + j0;
        out_row_off = (long)j0 << 8;
    }

#pragma unroll
    for (int i = 0; i < 2; ++i) {
        int col = cc + i * 32;
        long gbase = src_off + (long)col * row_stride + oct * 8;
        short v[8];
        if (isbf) {
            short8 p = *(const short8*)((const short*)src + gbase);
#pragma unroll
            for (int u = 0; u < 8; ++u) v[u] = p[u];
        } else {
            floatx4 q0 = *(const floatx4*)((const float*)src + gbase);
            floatx4 q1 = *(const floatx4*)((const float*)src + gbase + 4);
#pragma unroll
            for (int u = 0; u < 4; ++u) { v[u] = f2s(q0[u]); v[4 + u] = f2s(q1[u]); }
        }
        int row0 = oct * 8;
#pragma unroll
        for (int u = 0; u < 8; ++u) {
            int row = row0 + u;
            T[row][(((col >> 3) ^ (row & 7)) << 3) + (col & 7)] = v[u];
        }
    }
    __syncthreads();
    const int rr = tid >> 3;
#pragma unroll
    for (int i = 0; i < 2; ++i) {
        int row = rr + i * 32;
        short8 p = *(const short8*)&T[row][((oct ^ (row & 7)) << 3)];
        *(short8*)&dst[out_row_off + ((long)row << 8) + c0 + oct * 8] = p;
    }
}

// ---------------------------------------------------------------------------
// K1 (node 2): qkv GEMM (MFMA), 128x128 tile, 4 waves (64x64 quadrants).
// v branch writes BOTH vbb [c][n] (for dwconv) and vT [n][c] (for attv MFMA).
// ---------------------------------------------------------------------------
__global__ __launch_bounds__(256) void k_qkv_m3(const bf16* __restrict__ xT,
                                                const bf16* __restrict__ wT,
                                                bf16* __restrict__ qb,
                                                bf16* __restrict__ kb,
                                                bf16* __restrict__ vbb,
                                                bf16* __restrict__ vT,
                                                float* __restrict__ qss,
                                                float* __restrict__ kss) {
    __shared__ short As[128][72];
    __shared__ short Bs[128][72];
    const int id = blockIdx.x;                 // 1536 = 8 * 192
    const int swz = (id & 7) * 192 + (id >> 3);
    const int y = swz % 6;
    const int rest = swz / 6;
    const int n0 = (rest & 31) * 128;
    const int b = rest >> 5;
    const int j0 = y * 128;
    const int tid = threadIdx.x;
    const int wid = tid >> 6, l = tid & 63;
    const int wr = wid >> 1, wc = wid & 1;
    const int lm = l & 15, lk = (l >> 4) * 8;
    const int srow = tid >> 3, soct = tid & 7;
    floatx4 acc[4][4];
#pragma unroll
    for (int i = 0; i < 4; ++i)
#pragma unroll
        for (int j = 0; j < 4; ++j) acc[i][j] = (floatx4){0.f, 0.f, 0.f, 0.f};

    for (int k0 = 0; k0 < 256; k0 += 64) {
        __syncthreads();
#pragma unroll
        for (int i = 0; i < 4; ++i) {
            int row = srow + i * 32;
            *(short8*)&As[row][soct * 8] =
                *(const short8*)&wT[((j0 + row) << 8) + k0 + soct * 8];
            *(short8*)&Bs[row][soct * 8] =
                *(const short8*)&xT[(((b << 12) + n0 + row) << 8) + k0 + soct * 8];
        }
        __syncthreads();
#pragma unroll
        for (int h = 0; h < 2; ++h) {
            short8 af[4], bfv[4];
#pragma unroll
            for (int mt = 0; mt < 4; ++mt)
                af[mt] = *(const short8*)&As[wr * 64 + mt * 16 + lm][h * 32 + lk];
#pragma unroll
            for (int nt = 0; nt < 4; ++nt)
                bfv[nt] = *(const short8*)&Bs[wc * 64 + nt * 16 + lm][h * 32 + lk];
#pragma unroll
            for (int mt = 0; mt < 4; ++mt)
#pragma unroll
                for (int nt = 0; nt < 4; ++nt)
                    acc[mt][nt] = MFMA16(af[mt], bfv[nt], acc[mt][nt]);
        }
    }
    const int jbase = wr * 64 + (l >> 4) * 4;
    const int jq = (y & 1) * 128;
    if (y < 4) {
        bf16* dst = (y < 2) ? qb : kb;
#pragma unroll
        for (int mt = 0; mt < 4; ++mt)
#pragma unroll
            for (int nt = 0; nt < 4; ++nt) {
                int n = n0 + wc * 64 + nt * 16 + lm;
#pragma unroll
                for (int r = 0; r < 4; ++r)
                    dst[(((b << 8) + jq + jbase + mt * 16 + r) << 12) + n] =
                        f2b(acc[mt][nt][r]);
            }
        __syncthreads();
        float* red = (float*)&As[0][0];
#pragma unroll
        for (int mt = 0; mt < 4; ++mt)
#pragma unroll
            for (int r = 0; r < 4; ++r) {
                float s = 0.f;
#pragma unroll
                for (int nt = 0; nt < 4; ++nt) {
                    float v = acc[mt][nt][r];
                    s = fmaf(v, v, s);
                }
                red[(jbase + mt * 16 + r) * 32 + wc * 16 + lm] = s;
            }
        __syncthreads();
        if (tid < 128) {
            float s = 0.f;
#pragma unroll
            for (int i = 0; i < 32; ++i)
                s += red[tid * 32 + ((i + tid) & 31)];
            float* dsts = (y < 2) ? qss : kss;
            atomicAdd(&dsts[(b << 8) + jq + tid], s);
        }
    } else {
#pragma unroll
        for (int mt = 0; mt < 4; ++mt)
#pragma unroll
            for (int nt = 0; nt < 4; ++nt) {
                int n = n0 + wc * 64 + nt * 16 + lm;
                short4v pv;
#pragma unroll
                for (int r = 0; r < 4; ++r) {
                    float vf = acc[mt][nt][r];
                    vbb[(((b << 8) + jq + jbase + mt * 16 + r) << 12) + n] = f2b(vf);
                    pv[r] = f2s(vf);
                }
                *(short4v*)&((short*)vT)[(((long)(b << 12) + n) << 8) +
                                         jq + jbase + mt * 16] = pv;
            }
    }
}

// ---------------------------------------------------------------------------
// K_qkdw (node 3): id<64 -> fused QK^T+softmax; id>=64 -> dwconv+BN+GELU+T.
// ---------------------------------------------------------------------------
__global__ __launch_bounds__(256) void k_qkdw(const bf16* __restrict__ qb,
                                              const bf16* __restrict__ kb,
                                              const float* __restrict__ qss,
                                              const float* __restrict__ kss,
                                              const bf16* __restrict__ vbb,
                                              const float* __restrict__ prm,
                                              float* __restrict__ attn,
                                              bf16* __restrict__ convT) {
    __shared__ __align__(16) char smem[38368];
    const int id = blockIdx.x;
    const int tid = threadIdx.x;
    if (id < 64) {
        float (*AS)[32] = (float(*)[32])smem;
        const int h = id & 7, b = id >> 3;
        const int wid = tid >> 6, l = tid & 63;
        const int lm = l & 15, lk = (l >> 4) * 8;
        floatx4 acc[2][2];
#pragma unroll
        for (int i = 0; i < 2; ++i)
#pragma unroll
            for (int j = 0; j < 2; ++j) acc[i][j] = (floatx4){0.f, 0.f, 0.f, 0.f};
        const int cbase = (b << 8) + h * 32;
        for (int it = 0; it < 32; ++it) {
            int n = wid * 1024 + it * 32 + lk;
            short8 a0 = *(const short8*)&qb[((cbase + lm) << 12) + n];
            short8 a1 = *(const short8*)&qb[((cbase + 16 + lm) << 12) + n];
            short8 b0 = *(const short8*)&kb[((cbase + lm) << 12) + n];
            short8 b1 = *(const short8*)&kb[((cbase + 16 + lm) << 12) + n];
            acc[0][0] = MFMA16(a0, b0, acc[0][0]);
            acc[0][1] = MFMA16(a0, b1, acc[0][1]);
            acc[1][0] = MFMA16(a1, b0, acc[1][0]);
            acc[1][1] = MFMA16(a1, b1, acc[1][1]);
        }
        for (int i = tid; i < 1024; i += 256) ((float*)AS)[i] = 0.f;
        __syncthreads();
#pragma unroll
        for (int mt = 0; mt < 2; ++mt)
#pragma unroll
            for (int nt = 0; nt < 2; ++nt)
#pragma unroll
                for (int r = 0; r < 4; ++r)
                    atomicAdd(&AS[mt * 16 + (l >> 4) * 4 + r][nt * 16 + lm],
                              acc[mt][nt][r]);
        __syncthreads();
        if (tid < 32) {
            const int c = tid;
            float qsc = rsqrtf(fmaxf(qss[cbase + c], 1e-12f)) * prm[P_TEMP + h];
            float row[32];
            float m = -1e30f;
#pragma unroll
            for (int d = 0; d < 32; ++d) {
                row[d] = AS[c][d] * qsc * rsqrtf(fmaxf(kss[cbase + d], 1e-12f));
                m = fmaxf(m, row[d]);
            }
            float s = 0.f;
#pragma unroll
            for (int d = 0; d < 32; ++d) {
                row[d] = __expf(row[d] - m);
                s += row[d];
            }
            float inv = 1.0f / s;
            float* dst = attn + ((b * 8 + h) << 10) + c * 32;
#pragma unroll
            for (int d = 0; d < 32; ++d) dst[d] = row[d] * inv;
        }
    } else {
        float (*S)[18][66] = (float(*)[18][66])smem;
        float (*Wl)[11] = (float(*)[11])(smem + 38016);
        const int id2 = id - 64;
        const int y0 = (id2 & 3) * 16, c0 = ((id2 >> 2) & 31) * 8, b = id2 >> 7;
        if (tid < 144) {
            int ch = tid / 18, r = tid - ch * 18;
            int gy = y0 + r - 1;
            float* drow = &S[ch][r][0];
            if (gy < 0 || gy > 63) {
                for (int i = 0; i < 66; ++i) drow[i] = 0.f;
            } else {
                const short* src = (const short*)vbb +
                                   ((((b << 8) + c0 + ch) << 12) + gy * 64);
                drow[0] = 0.f;
                drow[65] = 0.f;
#pragma unroll
                for (int g = 0; g < 8; ++g) {
                    short8 p = *(const short8*)(src + g * 8);
#pragma unroll
                    for (int u = 0; u < 8; ++u) drow[1 + g * 8 + u] = s2f(p[u]);
                }
            }
        } else if (tid >= 248) {
            int ch = tid - 248;
            int c = c0 + ch;
            float scale = rsqrtf(prm[P_DWV + c] + 1e-3f) * prm[P_DWG + c];
#pragma unroll
            for (int e = 0; e < 9; ++e) Wl[ch][e] = prm[P_DWK + c * 9 + e] * scale;
            Wl[ch][10] = (prm[P_DWB + c] - prm[P_DWM + c]) * scale + prm[P_DWBT + c];
        }
        __syncthreads();
        const int row = tid >> 4, xl = tid & 15;
#pragma unroll
        for (int u = 0; u < 4; ++u) {
            int x = xl + u * 16;
            short8 o;
#pragma unroll
            for (int ch = 0; ch < 8; ++ch) {
                float acc = Wl[ch][10];
#pragma unroll
                for (int ky = 0; ky < 3; ++ky)
#pragma unroll
                    for (int kx = 0; kx < 3; ++kx)
                        acc = fmaf(S[ch][row + ky][x + kx], Wl[ch][ky * 3 + kx], acc);
                o[ch] = f2s(gelu_exact(acc));
            }
            *(short8*)&((short*)convT)[(((b << 12) + (y0 + row) * 64 + x) << 8) + c0] = o;
        }
    }
}

// ---------------------------------------------------------------------------
// K_attv_sm (node 4): id<1024 -> att = P @ v via MFMA (A = vT rows, B = P^T
// fragments built once per wave; one 16x16x32 MFMA covers K=32); LDS repack
// for coalesced attT stores; gap via LDS atomics.  id>=1024 -> spatial gate.
// ---------------------------------------------------------------------------
__global__ __launch_bounds__(256) void k_attv_sm(const float* __restrict__ attn,
                                                 const bf16* __restrict__ vT,
                                                 const bf16* __restrict__ convT,
                                                 const float* __restrict__ prm,
                                                 bf16* __restrict__ attT,
                                                 float* __restrict__ gap,
                                                 float* __restrict__ sigsm) {
    __shared__ __align__(16) char smem[20608];
    const int id = blockIdx.x;
    const int tid = threadIdx.x;
    if (id < 1024) {
        float (*P)[32] = (float(*)[32])smem;             // 4 KB
        short (*AT)[32] = (short(*)[32])(smem + 4096);   // 16 KB [256][32]
        float* gacc = (float*)(smem + 4096 + 16384);     // 128 B
        const int nq = id & 15, h = (id >> 4) & 7, b = id >> 7;
        for (int i = tid; i < 1024; i += 256)
            ((float*)P)[i] = attn[((b * 8 + h) << 10) + i];
        if (tid < 32) gacc[tid] = 0.f;
        __syncthreads();
        const int w = tid >> 6, l = tid & 63;
        const int lm = l & 15, lk = (l >> 4) * 8;
        // B fragments: B[col=c][k=d] = P[c][d]  (c0 = 0, 16)
        short8 bfr[2];
#pragma unroll
        for (int ct = 0; ct < 2; ++ct) {
            floatx4 p0 = *(const floatx4*)&P[ct * 16 + lm][lk];
            floatx4 p1 = *(const floatx4*)&P[ct * 16 + lm][lk + 4];
#pragma unroll
            for (int u = 0; u < 4; ++u) {
                bfr[ct][u] = f2s(p0[u]);
                bfr[ct][4 + u] = f2s(p1[u]);
            }
        }
        const floatx4 zero = {0.f, 0.f, 0.f, 0.f};
        const short* vTs = (const short*)vT;
#pragma unroll
        for (int t = 0; t < 4; ++t) {
            int nl = w * 64 + t * 16;                    // block-local n tile
            int n0 = nq * 256 + nl;
            // A frag: A[row=n][k=d] = vT[b][n0+lm][h*32 + lk..lk+7]
            short8 afr = *(const short8*)&vTs[(((long)(b << 12) + n0 + lm) << 8) +
                                              h * 32 + lk];
            floatx4 d0 = MFMA16(afr, bfr[0], zero);
            floatx4 d1 = MFMA16(afr, bfr[1], zero);
            int rowb = nl + (l >> 4) * 4;
            float s0 = 0.f, s1 = 0.f;
#pragma unroll
            for (int r = 0; r < 4; ++r) {
                AT[rowb + r][lm] = f2s(d0[r]);
                AT[rowb + r][16 + lm] = f2s(d1[r]);
                s0 += d0[r];
                s1 += d1[r];
            }
            atomicAdd(&gacc[lm], s0);
            atomicAdd(&gacc[16 + lm], s1);
        }
        __syncthreads();
        const long gb = ((long)(b << 12) + nq * 256) << 8;
#pragma unroll
        for (int q = 0; q < 4; ++q) {
            int s = tid + q * 256;
            int row = s >> 2, grp = s & 3;
            *(short8*)&((short*)attT)[gb + ((long)row << 8) + h * 32 + grp * 8] =
                *(const short8*)&AT[row][grp * 8];
        }
        if (tid < 32) atomicAdd(&gap[(b << 8) + h * 32 + tid], gacc[tid]);
    } else {
        float (*W1)[16] = (float(*)[16])smem;
        const int id2 = id - 1024;
        const int nx = id2 & 15, b = id2 >> 4;
        const int n = nx * 256 + tid;
        for (int i = tid; i < 4096; i += 256) W1[i >> 4][i & 15] = prm[P_SIW1 + i];
        __syncthreads();
        float acc[16];
#pragma unroll
        for (int o = 0; o < 16; ++o) acc[o] = 0.f;
        const bf16* src = convT + (((b << 12) + n) << 8);
#pragma unroll 4
        for (int g = 0; g < 32; ++g) {
            short8 p = *(const short8*)&src[g * 8];
#pragma unroll
            for (int u = 0; u < 8; ++u) {
                float v = s2f(p[u]);
                int c = g * 8 + u;
#pragma unroll
                for (int o = 0; o < 16; ++o) acc[o] = fmaf(v, W1[c][o], acc[o]);
            }
        }
        float sm = prm[P_SIB2];
#pragma unroll
        for (int o = 0; o < 16; ++o) {
            float t = acc[o] + prm[P_SIB1 + o];
            t = (t - prm[P_SIM + o]) * rsqrtf(prm[P_SIV + o] + 1e-3f) * prm[P_SIG + o] +
                prm[P_SIBT + o];
            sm = fmaf(gelu_exact(t), prm[P_SIW2 + o], sm);
        }
        sigsm[(b << 12) + n] = sigmoidf_(sm);
    }
}

// ---------------------------------------------------------------------------
// K9 (node 5): final projection (MFMA), 128x128 tile; inline channel gate.
// ---------------------------------------------------------------------------
__global__ __launch_bounds__(256) void k_proj_m3(const bf16* __restrict__ attT,
                                                 const bf16* __restrict__ convT,
                                                 const float* __restrict__ sigsm,
                                                 const float* __restrict__ gap,
                                                 const bf16* __restrict__ wpT,
                                                 const float* __restrict__ prm,
                                                 const unsigned* __restrict__ flag,
                                                 void* __restrict__ out) {
    __shared__ short As[128][72];
    __shared__ short Bs[128][72];
    __shared__ float scs[256];
    const bool isbf = (*flag != 0u);
    const int id = blockIdx.x;                 // 512 = 8 * 64
    const int swz = (id & 7) * 64 + (id >> 3);
    const int j0 = (swz & 1) * 128;
    const int rest = swz >> 1;
    const int n0 = (rest & 31) * 128;
    const int b = rest >> 5;
    const int tid = threadIdx.x;
    const int wid = tid >> 6, l = tid & 63;
    const int wr = wid >> 1, wc = wid & 1;
    const int lm = l & 15, lk = (l >> 4) * 8;
    const int srow = tid >> 3, soct = tid & 7;

    {
        float* gl = (float*)&As[0][0];
        float* rd = gl + 256;
        float* t1 = rd + 256;
        gl[tid] = gap[(b << 8) + tid] * (1.0f / 4096.0f);
        __syncthreads();
        const int o = tid >> 3, g = tid & 7;
        float s1 = 0.f;
#pragma unroll
        for (int i = 0; i < 32; ++i) {
            int c = g * 32 + i;
            s1 = fmaf(gl[c], prm[P_CIW1 + c * 32 + o], s1);
        }
        rd[o * 8 + g] = s1;
        __syncthreads();
        if (tid < 32) {
            float s = prm[P_CIB1 + tid];
#pragma unroll
            for (int g2 = 0; g2 < 8; ++g2) s += rd[tid * 8 + g2];
            s = (s - prm[P_CIM + tid]) * rsqrtf(prm[P_CIV + tid] + 1e-3f) *
                    prm[P_CIG + tid] + prm[P_CIBT + tid];
            t1[tid] = gelu_exact(s);
        }
        __syncthreads();
        float s = prm[P_CIB2 + tid];
#pragma unroll
        for (int o2 = 0; o2 < 32; ++o2)
            s = fmaf(t1[o2], prm[P_CIW2 + o2 * 256 + tid], s);
        scs[tid] = sigmoidf_(s);
    }

    floatx4 acc[4][4];
#pragma unroll
    for (int i = 0; i < 4; ++i)
#pragma unroll
        for (int j = 0; j < 4; ++j) acc[i][j] = (floatx4){0.f, 0.f, 0.f, 0.f};

    for (int k0 = 0; k0 < 256; k0 += 64) {
        __syncthreads();
#pragma unroll
        for (int i = 0; i < 4; ++i) {
            int row = srow + i * 32;
            *(short8*)&As[row][soct * 8] =
                *(const short8*)&wpT[((j0 + row) << 8) + k0 + soct * 8];
            int rbase = (((b << 12) + n0 + row) << 8) + k0 + soct * 8;
            short8 pa = *(const short8*)&attT[rbase];
            short8 pc = *(const short8*)&convT[rbase];
            float sv = sigsm[(b << 12) + n0 + row];
            short8 pz;
#pragma unroll
            for (int u = 0; u < 8; ++u)
                pz[u] = f2s(s2f(pa[u]) * sv + s2f(pc[u]) * scs[k0 + soct * 8 + u]);
            *(short8*)&Bs[row][soct * 8] = pz;
        }
        __syncthreads();
#pragma unroll
        for (int h = 0; h < 2; ++h) {
            short8 af[4], bfv[4];
#pragma unroll
            for (int mt = 0; mt < 4; ++mt)
                af[mt] = *(const short8*)&As[wr * 64 + mt * 16 + lm][h * 32 + lk];
#pragma unroll
            for (int nt = 0; nt < 4; ++nt)
                bfv[nt] = *(const short8*)&Bs[wc * 64 + nt * 16 + lm][h * 32 + lk];
#pragma unroll
            for (int mt = 0; mt < 4; ++mt)
#pragma unroll
                for (int nt = 0; nt < 4; ++nt)
                    acc[mt][nt] = MFMA16(af[mt], bfv[nt], acc[mt][nt]);
        }
    }
    const int jbase = j0 + wr * 64 + (l >> 4) * 4;
#pragma unroll
    for (int mt = 0; mt < 4; ++mt) {
        float bp[4];
#pragma unroll
        for (int r = 0; r < 4; ++r) bp[r] = prm[P_BPROJ + jbase + mt * 16 + r];
#pragma unroll
        for (int nt = 0; nt < 4; ++nt) {
            int n = n0 + wc * 64 + nt * 16 + lm;
#pragma unroll
            for (int r = 0; r < 4; ++r) {
                int idx = (((b << 8) + jbase + mt * 16 + r) << 12) + n;
                float val = acc[mt][nt][r] + bp[r];
                if (isbf) ((bf16*)out)[idx] = f2b(val);
                else ((float*)out)[idx] = val;
            }
        }
    }
}

// ---------------------------------------------------------------------------
extern "C" void kernel_launch(void* const* d_in, const int* in_sizes, int n_in,
                              void* d_out, int out_size, void* d_ws, size_t ws_size,
                              hipStream_t stream) {
    char* ws = (char*)d_ws;
    bf16*  vbb    = (bf16*) (ws);
    bf16*  xT     = (bf16*) (ws + 33554432);
    bf16*  attT   = (bf16*) (ws + 33554432);   // alias xT (dead after qkv)
    bf16*  qb     = (bf16*) (ws + 50331648);
    bf16*  kb     = (bf16*) (ws + 67108864);
    bf16*  wqkvT  = (bf16*) (ws + 83886080);
    bf16*  wprojT = (bf16*) (ws + 84279296);
    float* attn   = (float*)(ws + 84410368);
    float* qss    = (float*)(ws + 85721088);   // qss|kss|gap contiguous 24576B
    float* kss    = (float*)(ws + 85729280);
    float* gap    = (float*)(ws + 85737472);
    float* sigsm  = (float*)(ws + 85753856);
    float* prm    = (float*)(ws + 85884928);
    unsigned* flag = (unsigned*)(ws + 85985280);
    bf16*  convT  = (bf16*) (ws + 100663296);  // 96M..112M
    bf16*  vT     = (bf16*) (ws + 117440512);  // 112M..128M (new)

    CvtArgs a;
    const int map_src[24] = {3, 4, 5, 6, 7, 8, 9, 10, 11, 12, 13, 14, 15, 16, 17,
                             18, 19, 20, 21, 22, 23, 24, 25, 26};
    const int map_dst[24] = {P_BPROJ, P_DWK, P_DWB, P_DWG, P_DWBT, P_DWM, P_DWV,
                             P_CIG, P_CIBT, P_CIM, P_CIV, P_SIG, P_SIBT, P_SIM, P_SIV,
                             P_CIW1, P_CIB1, P_CIW2, P_CIB2, P_SIW1, P_SIB1, P_SIW2,
                             P_SIB2, P_TEMP};
    for (int i = 0; i < 24; ++i) {
        a.src[i] = d_in[map_src[i]];
        a.dst[i] = map_dst[i];
        a.cnt[i] = in_sizes[map_src[i]];
    }

    k_prept<<<2137, 256, 0, stream>>>(a, d_in[0], d_in[1], d_in[2],
                                      xT, wqkvT, wprojT, prm, flag, qss);
    k_qkv_m3<<<1536, 256, 0, stream>>>(xT, wqkvT, qb, kb, vbb, vT, qss, kss);
    k_qkdw<<<1088, 256, 0, stream>>>(qb, kb, qss, kss, vbb, prm, attn, convT);
    k_attv_sm<<<1152, 256, 0, stream>>>(attn, vT, convT, prm, attT, gap, sigsm);
    k_proj_m3<<<512, 256, 0, stream>>>(attT, convT, sigsm, gap,
                                       wprojT, prm, flag, d_out);
}

// Round 18
// 125.290 us; speedup vs baseline: 1.1520x; 1.0716x over previous
//
#include <hip/hip_runtime.h>
#include <hip/hip_bf16.h>
#include <math.h>

typedef __hip_bfloat16 bf16;
typedef __attribute__((ext_vector_type(8))) short short8;
typedef __attribute__((ext_vector_type(4))) short short4v;
typedef __attribute__((ext_vector_type(4))) float floatx4;

__device__ __forceinline__ bf16 f2b(float v) { return __float2bfloat16(v); }
__device__ __forceinline__ short f2s(float v) {
    bf16 h = __float2bfloat16(v);
    return *reinterpret_cast<short*>(&h);
}
__device__ __forceinline__ float s2f(short s) {
    union { unsigned u; float f; } t;
    t.u = ((unsigned)(unsigned short)s) << 16;
    return t.f;
}
__device__ __forceinline__ float gelu_exact(float x) {
    return 0.5f * x * (1.0f + erff(x * 0.70710678118654752440f));
}
__device__ __forceinline__ float sigmoidf_(float x) {
    return 1.0f / (1.0f + __expf(-x));
}
__device__ __forceinline__ float ldin(const void* p, int i, bool isbf) {
    return isbf ? s2f(((const short*)p)[i]) : ((const float*)p)[i];
}
#define MFMA16(a, b, c) __builtin_amdgcn_mfma_f32_16x16x32_bf16(a, b, c, 0, 0, 0)

// fp32 params block layout (offsets in floats)
#define P_DWK    0
#define P_DWB    2304
#define P_DWG    2560
#define P_DWBT   2816
#define P_DWM    3072
#define P_DWV    3328
#define P_CIW1   3584
#define P_CIB1   11776
#define P_CIG    11808
#define P_CIBT   11840
#define P_CIM    11872
#define P_CIV    11904
#define P_CIW2   11936
#define P_CIB2   20128
#define P_SIW1   20384
#define P_SIB1   24480
#define P_SIG    24496
#define P_SIBT   24512
#define P_SIM    24528
#define P_SIV    24544
#define P_SIW2   24560
#define P_SIB2   24576
#define P_TEMP   24577
#define P_BPROJ  24585

// ---------------------------------------------------------------------------
// helper: per-block dtype sniff of x's first 4096 words (L2-hot, ~1us total).
// ---------------------------------------------------------------------------
__device__ __forceinline__ bool block_sniff(const unsigned* __restrict__ x) {
    int cnt = 0;
    for (int i = threadIdx.x; i < 4096; i += 256) {
        unsigned lo = x[i] & 0xFFFFu;
        unsigned e = (lo >> 7) & 0xFFu;
        cnt += (e >= 0x66u && e <= 0x8Au) ? 1 : 0;
    }
    __shared__ int red[256];
    red[threadIdx.x] = cnt;
    __syncthreads();
    for (int o = 128; o > 0; o >>= 1) {
        if (threadIdx.x < o) red[threadIdx.x] += red[threadIdx.x + o];
        __syncthreads();
    }
    return red[0] > 2048;
}

// ---------------------------------------------------------------------------
// K_prept (node 1): merged prep + transposes (every block self-sniffs dtype).
// ---------------------------------------------------------------------------
struct CvtArgs { const void* src[24]; int dst[24]; int cnt[24]; };

__global__ __launch_bounds__(256) void k_prept(CvtArgs a,
                                               const void* __restrict__ x,
                                               const void* __restrict__ wqkv,
                                               const void* __restrict__ wproj,
                                               bf16* __restrict__ xT,
                                               bf16* __restrict__ wqkvT,
                                               bf16* __restrict__ wprojT,
                                               float* __restrict__ prm,
                                               unsigned* __restrict__ flag,
                                               float* __restrict__ accbuf) {
    __shared__ short T[64][72];
    const bool isbf = block_sniff((const unsigned*)x);
    const int id = blockIdx.x;
    const int tid = threadIdx.x;

    if (id >= 2112) {
        int e = id - 2112;
        if (e < 24) {
            const void* s = a.src[e];
            float* d = prm + a.dst[e];
            const int n = a.cnt[e];
            for (int i = tid; i < n; i += 256) d[i] = ldin(s, i, isbf);
        } else {
            for (int i = tid; i < 6144; i += 256) accbuf[i] = 0.f;
            if (tid == 0) *flag = isbf ? 1u : 0u;
        }
        return;
    }

    const int cc = tid >> 3, oct = tid & 7;
    const void* src;
    bf16* dst;
    long row_stride, src_off;
    int c0;
    long out_row_off;
    if (id < 2048) {
        int nx = id & 63, cy = (id >> 6) & 3, b = id >> 8;
        c0 = cy * 64;
        int n0 = nx * 64;
        src = x;
        dst = xT;
        row_stride = 4096;
        src_off = ((long)(b * 256 + c0) << 12) + n0;
        out_row_off = ((long)(b << 12) + n0) << 8;
    } else if (id < 2096) {
        int id2 = id - 2048;
        int jx = id2 % 12, cy = id2 / 12;
        c0 = cy * 64;
        int j0 = jx * 64;
        src = wqkv;
        dst = wqkvT;
        row_stride = 768;
        src_off = (long)c0 * 768 + j0;
        out_row_off = (long)j0 << 8;
    } else {
        int id3 = id - 2096;
        int jx = id3 & 3, cy = id3 >> 2;
        c0 = cy * 64;
        int j0 = jx * 64;
        src = wproj;
        dst = wprojT;
        row_stride = 256;
        src_off = (long)c0 * 256 + j0;
        out_row_off = (long)j0 << 8;
    }

#pragma unroll
    for (int i = 0; i < 2; ++i) {
        int col = cc + i * 32;
        long gbase = src_off + (long)col * row_stride + oct * 8;
        short v[8];
        if (isbf) {
            short8 p = *(const short8*)((const short*)src + gbase);
#pragma unroll
            for (int u = 0; u < 8; ++u) v[u] = p[u];
        } else {
            floatx4 q0 = *(const floatx4*)((const float*)src + gbase);
            floatx4 q1 = *(const floatx4*)((const float*)src + gbase + 4);
#pragma unroll
            for (int u = 0; u < 4; ++u) { v[u] = f2s(q0[u]); v[4 + u] = f2s(q1[u]); }
        }
        int row0 = oct * 8;
#pragma unroll
        for (int u = 0; u < 8; ++u) {
            int row = row0 + u;
            T[row][(((col >> 3) ^ (row & 7)) << 3) + (col & 7)] = v[u];
        }
    }
    __syncthreads();
    const int rr = tid >> 3;
#pragma unroll
    for (int i = 0; i < 2; ++i) {
        int row = rr + i * 32;
        short8 p = *(const short8*)&T[row][((oct ^ (row & 7)) << 3)];
        *(short8*)&dst[out_row_off + ((long)row << 8) + c0 + oct * 8] = p;
    }
}

// ---------------------------------------------------------------------------
// K1 (node 2): qkv GEMM (MFMA), 128x128 tile, 4 waves (64x64 quadrants).
// v branch writes BOTH vbb [c][n] (for dwconv) and vT [n][c] (for attv MFMA).
// ---------------------------------------------------------------------------
__global__ __launch_bounds__(256) void k_qkv_m3(const bf16* __restrict__ xT,
                                                const bf16* __restrict__ wT,
                                                bf16* __restrict__ qb,
                                                bf16* __restrict__ kb,
                                                bf16* __restrict__ vbb,
                                                bf16* __restrict__ vT,
                                                float* __restrict__ qss,
                                                float* __restrict__ kss) {
    __shared__ short As[128][72];
    __shared__ short Bs[128][72];
    const int id = blockIdx.x;                 // 1536 = 8 * 192
    const int swz = (id & 7) * 192 + (id >> 3);
    const int y = swz % 6;
    const int rest = swz / 6;
    const int n0 = (rest & 31) * 128;
    const int b = rest >> 5;
    const int j0 = y * 128;
    const int tid = threadIdx.x;
    const int wid = tid >> 6, l = tid & 63;
    const int wr = wid >> 1, wc = wid & 1;
    const int lm = l & 15, lk = (l >> 4) * 8;
    const int srow = tid >> 3, soct = tid & 7;
    floatx4 acc[4][4];
#pragma unroll
    for (int i = 0; i < 4; ++i)
#pragma unroll
        for (int j = 0; j < 4; ++j) acc[i][j] = (floatx4){0.f, 0.f, 0.f, 0.f};

    for (int k0 = 0; k0 < 256; k0 += 64) {
        __syncthreads();
#pragma unroll
        for (int i = 0; i < 4; ++i) {
            int row = srow + i * 32;
            *(short8*)&As[row][soct * 8] =
                *(const short8*)&wT[((j0 + row) << 8) + k0 + soct * 8];
            *(short8*)&Bs[row][soct * 8] =
                *(const short8*)&xT[(((b << 12) + n0 + row) << 8) + k0 + soct * 8];
        }
        __syncthreads();
#pragma unroll
        for (int h = 0; h < 2; ++h) {
            short8 af[4], bfv[4];
#pragma unroll
            for (int mt = 0; mt < 4; ++mt)
                af[mt] = *(const short8*)&As[wr * 64 + mt * 16 + lm][h * 32 + lk];
#pragma unroll
            for (int nt = 0; nt < 4; ++nt)
                bfv[nt] = *(const short8*)&Bs[wc * 64 + nt * 16 + lm][h * 32 + lk];
#pragma unroll
            for (int mt = 0; mt < 4; ++mt)
#pragma unroll
                for (int nt = 0; nt < 4; ++nt)
                    acc[mt][nt] = MFMA16(af[mt], bfv[nt], acc[mt][nt]);
        }
    }
    const int jbase = wr * 64 + (l >> 4) * 4;
    const int jq = (y & 1) * 128;
    if (y < 4) {
        bf16* dst = (y < 2) ? qb : kb;
#pragma unroll
        for (int mt = 0; mt < 4; ++mt)
#pragma unroll
            for (int nt = 0; nt < 4; ++nt) {
                int n = n0 + wc * 64 + nt * 16 + lm;
#pragma unroll
                for (int r = 0; r < 4; ++r)
                    dst[(((b << 8) + jq + jbase + mt * 16 + r) << 12) + n] =
                        f2b(acc[mt][nt][r]);
            }
        __syncthreads();
        float* red = (float*)&As[0][0];
#pragma unroll
        for (int mt = 0; mt < 4; ++mt)
#pragma unroll
            for (int r = 0; r < 4; ++r) {
                float s = 0.f;
#pragma unroll
                for (int nt = 0; nt < 4; ++nt) {
                    float v = acc[mt][nt][r];
                    s = fmaf(v, v, s);
                }
                red[(jbase + mt * 16 + r) * 32 + wc * 16 + lm] = s;
            }
        __syncthreads();
        if (tid < 128) {
            float s = 0.f;
#pragma unroll
            for (int i = 0; i < 32; ++i)
                s += red[tid * 32 + ((i + tid) & 31)];
            float* dsts = (y < 2) ? qss : kss;
            atomicAdd(&dsts[(b << 8) + jq + tid], s);
        }
    } else {
#pragma unroll
        for (int mt = 0; mt < 4; ++mt)
#pragma unroll
            for (int nt = 0; nt < 4; ++nt) {
                int n = n0 + wc * 64 + nt * 16 + lm;
                short4v pv;
#pragma unroll
                for (int r = 0; r < 4; ++r) {
                    float vf = acc[mt][nt][r];
                    vbb[(((b << 8) + jq + jbase + mt * 16 + r) << 12) + n] = f2b(vf);
                    pv[r] = f2s(vf);
                }
                *(short4v*)&((short*)vT)[(((long)(b << 12) + n) << 8) +
                                         jq + jbase + mt * 16] = pv;
            }
    }
}

// ---------------------------------------------------------------------------
// K_qkdw (node 3): id<64 -> fused QK^T+softmax; id>=64 -> dwconv+BN+GELU+T.
// ---------------------------------------------------------------------------
__global__ __launch_bounds__(256) void k_qkdw(const bf16* __restrict__ qb,
                                              const bf16* __restrict__ kb,
                                              const float* __restrict__ qss,
                                              const float* __restrict__ kss,
                                              const bf16* __restrict__ vbb,
                                              const float* __restrict__ prm,
                                              float* __restrict__ attn,
                                              bf16* __restrict__ convT) {
    __shared__ __align__(16) char smem[38368];
    const int id = blockIdx.x;
    const int tid = threadIdx.x;
    if (id < 64) {
        float (*AS)[32] = (float(*)[32])smem;
        const int h = id & 7, b = id >> 3;
        const int wid = tid >> 6, l = tid & 63;
        const int lm = l & 15, lk = (l >> 4) * 8;
        floatx4 acc[2][2];
#pragma unroll
        for (int i = 0; i < 2; ++i)
#pragma unroll
            for (int j = 0; j < 2; ++j) acc[i][j] = (floatx4){0.f, 0.f, 0.f, 0.f};
        const int cbase = (b << 8) + h * 32;
        for (int it = 0; it < 32; ++it) {
            int n = wid * 1024 + it * 32 + lk;
            short8 a0 = *(const short8*)&qb[((cbase + lm) << 12) + n];
            short8 a1 = *(const short8*)&qb[((cbase + 16 + lm) << 12) + n];
            short8 b0 = *(const short8*)&kb[((cbase + lm) << 12) + n];
            short8 b1 = *(const short8*)&kb[((cbase + 16 + lm) << 12) + n];
            acc[0][0] = MFMA16(a0, b0, acc[0][0]);
            acc[0][1] = MFMA16(a0, b1, acc[0][1]);
            acc[1][0] = MFMA16(a1, b0, acc[1][0]);
            acc[1][1] = MFMA16(a1, b1, acc[1][1]);
        }
        for (int i = tid; i < 1024; i += 256) ((float*)AS)[i] = 0.f;
        __syncthreads();
#pragma unroll
        for (int mt = 0; mt < 2; ++mt)
#pragma unroll
            for (int nt = 0; nt < 2; ++nt)
#pragma unroll
                for (int r = 0; r < 4; ++r)
                    atomicAdd(&AS[mt * 16 + (l >> 4) * 4 + r][nt * 16 + lm],
                              acc[mt][nt][r]);
        __syncthreads();
        if (tid < 32) {
            const int c = tid;
            float qsc = rsqrtf(fmaxf(qss[cbase + c], 1e-12f)) * prm[P_TEMP + h];
            float row[32];
            float m = -1e30f;
#pragma unroll
            for (int d = 0; d < 32; ++d) {
                row[d] = AS[c][d] * qsc * rsqrtf(fmaxf(kss[cbase + d], 1e-12f));
                m = fmaxf(m, row[d]);
            }
            float s = 0.f;
#pragma unroll
            for (int d = 0; d < 32; ++d) {
                row[d] = __expf(row[d] - m);
                s += row[d];
            }
            float inv = 1.0f / s;
            float* dst = attn + ((b * 8 + h) << 10) + c * 32;
#pragma unroll
            for (int d = 0; d < 32; ++d) dst[d] = row[d] * inv;
        }
    } else {
        float (*S)[18][66] = (float(*)[18][66])smem;
        float (*Wl)[11] = (float(*)[11])(smem + 38016);
        const int id2 = id - 64;
        const int y0 = (id2 & 3) * 16, c0 = ((id2 >> 2) & 31) * 8, b = id2 >> 7;
        if (tid < 144) {
            int ch = tid / 18, r = tid - ch * 18;
            int gy = y0 + r - 1;
            float* drow = &S[ch][r][0];
            if (gy < 0 || gy > 63) {
                for (int i = 0; i < 66; ++i) drow[i] = 0.f;
            } else {
                const short* src = (const short*)vbb +
                                   ((((b << 8) + c0 + ch) << 12) + gy * 64);
                drow[0] = 0.f;
                drow[65] = 0.f;
#pragma unroll
                for (int g = 0; g < 8; ++g) {
                    short8 p = *(const short8*)(src + g * 8);
#pragma unroll
                    for (int u = 0; u < 8; ++u) drow[1 + g * 8 + u] = s2f(p[u]);
                }
            }
        } else if (tid >= 248) {
            int ch = tid - 248;
            int c = c0 + ch;
            float scale = rsqrtf(prm[P_DWV + c] + 1e-3f) * prm[P_DWG + c];
#pragma unroll
            for (int e = 0; e < 9; ++e) Wl[ch][e] = prm[P_DWK + c * 9 + e] * scale;
            Wl[ch][10] = (prm[P_DWB + c] - prm[P_DWM + c]) * scale + prm[P_DWBT + c];
        }
        __syncthreads();
        const int row = tid >> 4, xl = tid & 15;
#pragma unroll
        for (int u = 0; u < 4; ++u) {
            int x = xl + u * 16;
            short8 o;
#pragma unroll
            for (int ch = 0; ch < 8; ++ch) {
                float acc = Wl[ch][10];
#pragma unroll
                for (int ky = 0; ky < 3; ++ky)
#pragma unroll
                    for (int kx = 0; kx < 3; ++kx)
                        acc = fmaf(S[ch][row + ky][x + kx], Wl[ch][ky * 3 + kx], acc);
                o[ch] = f2s(gelu_exact(acc));
            }
            *(short8*)&((short*)convT)[(((b << 12) + (y0 + row) * 64 + x) << 8) + c0] = o;
        }
    }
}

// ---------------------------------------------------------------------------
// K_attv_sm (node 4): id<1024 -> att = P @ v via MFMA;
// id>=1024 (512 blocks) -> spatial gate via MFMA:
//   per wave: 16 n-rows; 8 K-steps of {A=convT row short8, B=bf16(si_w1)},
//   epilogue bias+BN+GELU*w2 + 16-lane shfl reduce over o.
// ---------------------------------------------------------------------------
__global__ __launch_bounds__(256) void k_attv_sm(const float* __restrict__ attn,
                                                 const bf16* __restrict__ vT,
                                                 const bf16* __restrict__ convT,
                                                 const float* __restrict__ prm,
                                                 bf16* __restrict__ attT,
                                                 float* __restrict__ gap,
                                                 float* __restrict__ sigsm) {
    __shared__ __align__(16) char smem[20608];
    const int id = blockIdx.x;
    const int tid = threadIdx.x;
    if (id < 1024) {
        float (*P)[32] = (float(*)[32])smem;             // 4 KB
        short (*AT)[32] = (short(*)[32])(smem + 4096);   // 16 KB [256][32]
        float* gacc = (float*)(smem + 4096 + 16384);     // 128 B
        const int nq = id & 15, h = (id >> 4) & 7, b = id >> 7;
        for (int i = tid; i < 1024; i += 256)
            ((float*)P)[i] = attn[((b * 8 + h) << 10) + i];
        if (tid < 32) gacc[tid] = 0.f;
        __syncthreads();
        const int w = tid >> 6, l = tid & 63;
        const int lm = l & 15, lk = (l >> 4) * 8;
        short8 bfr[2];
#pragma unroll
        for (int ct = 0; ct < 2; ++ct) {
            floatx4 p0 = *(const floatx4*)&P[ct * 16 + lm][lk];
            floatx4 p1 = *(const floatx4*)&P[ct * 16 + lm][lk + 4];
#pragma unroll
            for (int u = 0; u < 4; ++u) {
                bfr[ct][u] = f2s(p0[u]);
                bfr[ct][4 + u] = f2s(p1[u]);
            }
        }
        const floatx4 zero = {0.f, 0.f, 0.f, 0.f};
        const short* vTs = (const short*)vT;
#pragma unroll
        for (int t = 0; t < 4; ++t) {
            int nl = w * 64 + t * 16;
            int n0 = nq * 256 + nl;
            short8 afr = *(const short8*)&vTs[(((long)(b << 12) + n0 + lm) << 8) +
                                              h * 32 + lk];
            floatx4 d0 = MFMA16(afr, bfr[0], zero);
            floatx4 d1 = MFMA16(afr, bfr[1], zero);
            int rowb = nl + (l >> 4) * 4;
            float s0 = 0.f, s1 = 0.f;
#pragma unroll
            for (int r = 0; r < 4; ++r) {
                AT[rowb + r][lm] = f2s(d0[r]);
                AT[rowb + r][16 + lm] = f2s(d1[r]);
                s0 += d0[r];
                s1 += d1[r];
            }
            atomicAdd(&gacc[lm], s0);
            atomicAdd(&gacc[16 + lm], s1);
        }
        __syncthreads();
        const long gb = ((long)(b << 12) + nq * 256) << 8;
#pragma unroll
        for (int q = 0; q < 4; ++q) {
            int s = tid + q * 256;
            int row = s >> 2, grp = s & 3;
            *(short8*)&((short*)attT)[gb + ((long)row << 8) + h * 32 + grp * 8] =
                *(const short8*)&AT[row][grp * 8];
        }
        if (tid < 32) atomicAdd(&gap[(b << 8) + h * 32 + tid], gacc[tid]);
    } else {
        // ----- spatial gate via MFMA -----
        float (*W1s)[17] = (float(*)[17])smem;           // 256*17*4 = 17408 B
        const int id2 = id - 1024;                       // 0..511
        const int nx = id2 & 63, b = id2 >> 6;
        for (int i = tid; i < 4096; i += 256) W1s[i >> 4][i & 15] = prm[P_SIW1 + i];
        __syncthreads();
        const int w = tid >> 6, l = tid & 63;
        const int lm = l & 15, lk = (l >> 4) * 8;
        const int n0 = nx * 64 + w * 16;                 // wave's 16 n-rows
        floatx4 acc = {0.f, 0.f, 0.f, 0.f};
        const short* cs = (const short*)convT;
#pragma unroll
        for (int ks = 0; ks < 8; ++ks) {
            int k0 = ks * 32;
            short8 afr = *(const short8*)&cs[(((long)(b << 12) + n0 + lm) << 8) +
                                             k0 + lk];
            short8 bfr;
#pragma unroll
            for (int i = 0; i < 8; ++i) bfr[i] = f2s(W1s[k0 + lk + i][lm]);
            acc = MFMA16(afr, bfr, acc);
        }
        const int o = lm;
        const float b1v = prm[P_SIB1 + o];
        const float scale = rsqrtf(prm[P_SIV + o] + 1e-3f) * prm[P_SIG + o];
        const float shift = prm[P_SIBT + o] - prm[P_SIM + o] * scale;
        const float w2v = prm[P_SIW2 + o];
        float part[4];
#pragma unroll
        for (int r = 0; r < 4; ++r) {
            float t = (acc[r] + b1v) * scale + shift;
            part[r] = gelu_exact(t) * w2v;
        }
#pragma unroll
        for (int off = 1; off < 16; off <<= 1)
#pragma unroll
            for (int r = 0; r < 4; ++r)
                part[r] += __shfl_xor(part[r], off, 64);
        if (lm == 0) {
            int nrow = n0 + (l >> 4) * 4;
            float b2 = prm[P_SIB2];
#pragma unroll
            for (int r = 0; r < 4; ++r)
                sigsm[(b << 12) + nrow + r] = sigmoidf_(b2 + part[r]);
        }
    }
}

// ---------------------------------------------------------------------------
// K9 (node 5): final projection (MFMA), 128x128 tile; inline channel gate.
// ---------------------------------------------------------------------------
__global__ __launch_bounds__(256) void k_proj_m3(const bf16* __restrict__ attT,
                                                 const bf16* __restrict__ convT,
                                                 const float* __restrict__ sigsm,
                                                 const float* __restrict__ gap,
                                                 const bf16* __restrict__ wpT,
                                                 const float* __restrict__ prm,
                                                 const unsigned* __restrict__ flag,
                                                 void* __restrict__ out) {
    __shared__ short As[128][72];
    __shared__ short Bs[128][72];
    __shared__ float scs[256];
    const bool isbf = (*flag != 0u);
    const int id = blockIdx.x;                 // 512 = 8 * 64
    const int swz = (id & 7) * 64 + (id >> 3);
    const int j0 = (swz & 1) * 128;
    const int rest = swz >> 1;
    const int n0 = (rest & 31) * 128;
    const int b = rest >> 5;
    const int tid = threadIdx.x;
    const int wid = tid >> 6, l = tid & 63;
    const int wr = wid >> 1, wc = wid & 1;
    const int lm = l & 15, lk = (l >> 4) * 8;
    const int srow = tid >> 3, soct = tid & 7;

    {
        float* gl = (float*)&As[0][0];
        float* rd = gl + 256;
        float* t1 = rd + 256;
        gl[tid] = gap[(b << 8) + tid] * (1.0f / 4096.0f);
        __syncthreads();
        const int o = tid >> 3, g = tid & 7;
        float s1 = 0.f;
#pragma unroll
        for (int i = 0; i < 32; ++i) {
            int c = g * 32 + i;
            s1 = fmaf(gl[c], prm[P_CIW1 + c * 32 + o], s1);
        }
        rd[o * 8 + g] = s1;
        __syncthreads();
        if (tid < 32) {
            float s = prm[P_CIB1 + tid];
#pragma unroll
            for (int g2 = 0; g2 < 8; ++g2) s += rd[tid * 8 + g2];
            s = (s - prm[P_CIM + tid]) * rsqrtf(prm[P_CIV + tid] + 1e-3f) *
                    prm[P_CIG + tid] + prm[P_CIBT + tid];
            t1[tid] = gelu_exact(s);
        }
        __syncthreads();
        float s = prm[P_CIB2 + tid];
#pragma unroll
        for (int o2 = 0; o2 < 32; ++o2)
            s = fmaf(t1[o2], prm[P_CIW2 + o2 * 256 + tid], s);
        scs[tid] = sigmoidf_(s);
    }

    floatx4 acc[4][4];
#pragma unroll
    for (int i = 0; i < 4; ++i)
#pragma unroll
        for (int j = 0; j < 4; ++j) acc[i][j] = (floatx4){0.f, 0.f, 0.f, 0.f};

    for (int k0 = 0; k0 < 256; k0 += 64) {
        __syncthreads();
#pragma unroll
        for (int i = 0; i < 4; ++i) {
            int row = srow + i * 32;
            *(short8*)&As[row][soct * 8] =
                *(const short8*)&wpT[((j0 + row) << 8) + k0 + soct * 8];
            int rbase = (((b << 12) + n0 + row) << 8) + k0 + soct * 8;
            short8 pa = *(const short8*)&attT[rbase];
            short8 pc = *(const short8*)&convT[rbase];
            float sv = sigsm[(b << 12) + n0 + row];
            short8 pz;
#pragma unroll
            for (int u = 0; u < 8; ++u)
                pz[u] = f2s(s2f(pa[u]) * sv + s2f(pc[u]) * scs[k0 + soct * 8 + u]);
            *(short8*)&Bs[row][soct * 8] = pz;
        }
        __syncthreads();
#pragma unroll
        for (int h = 0; h < 2; ++h) {
            short8 af[4], bfv[4];
#pragma unroll
            for (int mt = 0; mt < 4; ++mt)
                af[mt] = *(const short8*)&As[wr * 64 + mt * 16 + lm][h * 32 + lk];
#pragma unroll
            for (int nt = 0; nt < 4; ++nt)
                bfv[nt] = *(const short8*)&Bs[wc * 64 + nt * 16 + lm][h * 32 + lk];
#pragma unroll
            for (int mt = 0; mt < 4; ++mt)
#pragma unroll
                for (int nt = 0; nt < 4; ++nt)
                    acc[mt][nt] = MFMA16(af[mt], bfv[nt], acc[mt][nt]);
        }
    }
    const int jbase = j0 + wr * 64 + (l >> 4) * 4;
#pragma unroll
    for (int mt = 0; mt < 4; ++mt) {
        float bp[4];
#pragma unroll
        for (int r = 0; r < 4; ++r) bp[r] = prm[P_BPROJ + jbase + mt * 16 + r];
#pragma unroll
        for (int nt = 0; nt < 4; ++nt) {
            int n = n0 + wc * 64 + nt * 16 + lm;
#pragma unroll
            for (int r = 0; r < 4; ++r) {
                int idx = (((b << 8) + jbase + mt * 16 + r) << 12) + n;
                float val = acc[mt][nt][r] + bp[r];
                if (isbf) ((bf16*)out)[idx] = f2b(val);
                else ((float*)out)[idx] = val;
            }
        }
    }
}

// ---------------------------------------------------------------------------
extern "C" void kernel_launch(void* const* d_in, const int* in_sizes, int n_in,
                              void* d_out, int out_size, void* d_ws, size_t ws_size,
                              hipStream_t stream) {
    char* ws = (char*)d_ws;
    bf16*  vbb    = (bf16*) (ws);
    bf16*  xT     = (bf16*) (ws + 33554432);
    bf16*  attT   = (bf16*) (ws + 33554432);   // alias xT (dead after qkv)
    bf16*  qb     = (bf16*) (ws + 50331648);
    bf16*  kb     = (bf16*) (ws + 67108864);
    bf16*  wqkvT  = (bf16*) (ws + 83886080);
    bf16*  wprojT = (bf16*) (ws + 84279296);
    float* attn   = (float*)(ws + 84410368);
    float* qss    = (float*)(ws + 85721088);   // qss|kss|gap contiguous 24576B
    float* kss    = (float*)(ws + 85729280);
    float* gap    = (float*)(ws + 85737472);
    float* sigsm  = (float*)(ws + 85753856);
    float* prm    = (float*)(ws + 85884928);
    unsigned* flag = (unsigned*)(ws + 85985280);
    bf16*  convT  = (bf16*) (ws + 100663296);  // 96M..112M
    bf16*  vT     = (bf16*) (ws + 117440512);  // 112M..128M

    CvtArgs a;
    const int map_src[24] = {3, 4, 5, 6, 7, 8, 9, 10, 11, 12, 13, 14, 15, 16, 17,
                             18, 19, 20, 21, 22, 23, 24, 25, 26};
    const int map_dst[24] = {P_BPROJ, P_DWK, P_DWB, P_DWG, P_DWBT, P_DWM, P_DWV,
                             P_CIG, P_CIBT, P_CIM, P_CIV, P_SIG, P_SIBT, P_SIM, P_SIV,
                             P_CIW1, P_CIB1, P_CIW2, P_CIB2, P_SIW1, P_SIB1, P_SIW2,
                             P_SIB2, P_TEMP};
    for (int i = 0; i < 24; ++i) {
        a.src[i] = d_in[map_src[i]];
        a.dst[i] = map_dst[i];
        a.cnt[i] = in_sizes[map_src[i]];
    }

    k_prept<<<2137, 256, 0, stream>>>(a, d_in[0], d_in[1], d_in[2],
                                      xT, wqkvT, wprojT, prm, flag, qss);
    k_qkv_m3<<<1536, 256, 0, stream>>>(xT, wqkvT, qb, kb, vbb, vT, qss, kss);
    k_qkdw<<<1088, 256, 0, stream>>>(qb, kb, qss, kss, vbb, prm, attn, convT);
    k_attv_sm<<<1536, 256, 0, stream>>>(attn, vT, convT, prm, attT, gap, sigsm);
    k_proj_m3<<<512, 256, 0, stream>>>(attT, convT, sigsm, gap,
                                       wprojT, prm, flag, d_out);
}

// Round 20
// 125.084 us; speedup vs baseline: 1.1539x; 1.0016x over previous
//
#include <hip/hip_runtime.h>
#include <hip/hip_bf16.h>
#include <math.h>

typedef __hip_bfloat16 bf16;
typedef __attribute__((ext_vector_type(8))) short short8;
typedef __attribute__((ext_vector_type(4))) short short4v;
typedef __attribute__((ext_vector_type(4))) float floatx4;

__device__ __forceinline__ bf16 f2b(float v) { return __float2bfloat16(v); }
__device__ __forceinline__ short f2s(float v) {
    bf16 h = __float2bfloat16(v);
    return *reinterpret_cast<short*>(&h);
}
__device__ __forceinline__ float s2f(short s) {
    union { unsigned u; float f; } t;
    t.u = ((unsigned)(unsigned short)s) << 16;
    return t.f;
}
__device__ __forceinline__ float gelu_exact(float x) {
    return 0.5f * x * (1.0f + erff(x * 0.70710678118654752440f));
}
__device__ __forceinline__ float sigmoidf_(float x) {
    return 1.0f / (1.0f + __expf(-x));
}
__device__ __forceinline__ float ldin(const void* p, int i, bool isbf) {
    return isbf ? s2f(((const short*)p)[i]) : ((const float*)p)[i];
}
#define MFMA16(a, b, c) __builtin_amdgcn_mfma_f32_16x16x32_bf16(a, b, c, 0, 0, 0)

// fp32 params block layout (offsets in floats)
#define P_DWK    0
#define P_DWB    2304
#define P_DWG    2560
#define P_DWBT   2816
#define P_DWM    3072
#define P_DWV    3328
#define P_CIW1   3584
#define P_CIB1   11776
#define P_CIG    11808
#define P_CIBT   11840
#define P_CIM    11872
#define P_CIV    11904
#define P_CIW2   11936
#define P_CIB2   20128
#define P_SIW1   20384
#define P_SIB1   24480
#define P_SIG    24496
#define P_SIBT   24512
#define P_SIM    24528
#define P_SIV    24544
#define P_SIW2   24560
#define P_SIB2   24576
#define P_TEMP   24577
#define P_BPROJ  24585

// ---------------------------------------------------------------------------
// helper: per-block dtype sniff of x's first 4096 words (L2-hot, ~1us total).
// ---------------------------------------------------------------------------
__device__ __forceinline__ bool block_sniff(const unsigned* __restrict__ x) {
    int cnt = 0;
    for (int i = threadIdx.x; i < 4096; i += 256) {
        unsigned lo = x[i] & 0xFFFFu;
        unsigned e = (lo >> 7) & 0xFFu;
        cnt += (e >= 0x66u && e <= 0x8Au) ? 1 : 0;
    }
    __shared__ int red[256];
    red[threadIdx.x] = cnt;
    __syncthreads();
    for (int o = 128; o > 0; o >>= 1) {
        if (threadIdx.x < o) red[threadIdx.x] += red[threadIdx.x + o];
        __syncthreads();
    }
    return red[0] > 2048;
}

// ---------------------------------------------------------------------------
// K_prept (node 1): merged prep + transposes (every block self-sniffs dtype).
// ---------------------------------------------------------------------------
struct CvtArgs { const void* src[24]; int dst[24]; int cnt[24]; };

__global__ __launch_bounds__(256) void k_prept(CvtArgs a,
                                               const void* __restrict__ x,
                                               const void* __restrict__ wqkv,
                                               const void* __restrict__ wproj,
                                               bf16* __restrict__ xT,
                                               bf16* __restrict__ wqkvT,
                                               bf16* __restrict__ wprojT,
                                               float* __restrict__ prm,
                                               unsigned* __restrict__ flag,
                                               float* __restrict__ accbuf) {
    __shared__ short T[64][72];
    const bool isbf = block_sniff((const unsigned*)x);
    const int id = blockIdx.x;
    const int tid = threadIdx.x;

    if (id >= 2112) {
        int e = id - 2112;
        if (e < 24) {
            const void* s = a.src[e];
            float* d = prm + a.dst[e];
            const int n = a.cnt[e];
            for (int i = tid; i < n; i += 256) d[i] = ldin(s, i, isbf);
        } else {
            for (int i = tid; i < 6144; i += 256) accbuf[i] = 0.f;
            if (tid == 0) *flag = isbf ? 1u : 0u;
        }
        return;
    }

    const int cc = tid >> 3, oct = tid & 7;
    const void* src;
    bf16* dst;
    long row_stride, src_off;
    int c0;
    long out_row_off;
    if (id < 2048) {
        int nx = id & 63, cy = (id >> 6) & 3, b = id >> 8;
        c0 = cy * 64;
        int n0 = nx * 64;
        src = x;
        dst = xT;
        row_stride = 4096;
        src_off = ((long)(b * 256 + c0) << 12) + n0;
        out_row_off = ((long)(b << 12) + n0) << 8;
    } else if (id < 2096) {
        int id2 = id - 2048;
        int jx = id2 % 12, cy = id2 / 12;
        c0 = cy * 64;
        int j0 = jx * 64;
        src = wqkv;
        dst = wqkvT;
        row_stride = 768;
        src_off = (long)c0 * 768 + j0;
        out_row_off = (long)j0 << 8;
    } else {
        int id3 = id - 2096;
        int jx = id3 & 3, cy = id3 >> 2;
        c0 = cy * 64;
        int j0 = jx * 64;
        src = wproj;
        dst = wprojT;
        row_stride = 256;
        src_off = (long)c0 * 256 + j0;
        out_row_off = (long)j0 << 8;
    }

#pragma unroll
    for (int i = 0; i < 2; ++i) {
        int col = cc + i * 32;
        long gbase = src_off + (long)col * row_stride + oct * 8;
        short v[8];
        if (isbf) {
            short8 p = *(const short8*)((const short*)src + gbase);
#pragma unroll
            for (int u = 0; u < 8; ++u) v[u] = p[u];
        } else {
            floatx4 q0 = *(const floatx4*)((const float*)src + gbase);
            floatx4 q1 = *(const floatx4*)((const float*)src + gbase + 4);
#pragma unroll
            for (int u = 0; u < 4; ++u) { v[u] = f2s(q0[u]); v[4 + u] = f2s(q1[u]); }
        }
        int row0 = oct * 8;
#pragma unroll
        for (int u = 0; u < 8; ++u) {
            int row = row0 + u;
            T[row][(((col >> 3) ^ (row & 7)) << 3) + (col & 7)] = v[u];
        }
    }
    __syncthreads();
    const int rr = tid >> 3;
#pragma unroll
    for (int i = 0; i < 2; ++i) {
        int row = rr + i * 32;
        short8 p = *(const short8*)&T[row][((oct ^ (row & 7)) << 3)];
        *(short8*)&dst[out_row_off + ((long)row << 8) + c0 + oct * 8] = p;
    }
}

// ---------------------------------------------------------------------------
// K1 (node 2): qkv GEMM (MFMA), 128x128 tile, 4 waves (64x64 quadrants).
// v branch writes BOTH vbb [c][n] (for dwconv) and vT [n][c] (for attv MFMA).
// ---------------------------------------------------------------------------
__global__ __launch_bounds__(256) void k_qkv_m3(const bf16* __restrict__ xT,
                                                const bf16* __restrict__ wT,
                                                bf16* __restrict__ qb,
                                                bf16* __restrict__ kb,
                                                bf16* __restrict__ vbb,
                                                bf16* __restrict__ vT,
                                                float* __restrict__ qss,
                                                float* __restrict__ kss) {
    __shared__ short As[128][72];
    __shared__ short Bs[128][72];
    const int id = blockIdx.x;                 // 1536 = 8 * 192
    const int swz = (id & 7) * 192 + (id >> 3);
    const int y = swz % 6;
    const int rest = swz / 6;
    const int n0 = (rest & 31) * 128;
    const int b = rest >> 5;
    const int j0 = y * 128;
    const int tid = threadIdx.x;
    const int wid = tid >> 6, l = tid & 63;
    const int wr = wid >> 1, wc = wid & 1;
    const int lm = l & 15, lk = (l >> 4) * 8;
    const int srow = tid >> 3, soct = tid & 7;
    floatx4 acc[4][4];
#pragma unroll
    for (int i = 0; i < 4; ++i)
#pragma unroll
        for (int j = 0; j < 4; ++j) acc[i][j] = (floatx4){0.f, 0.f, 0.f, 0.f};

    for (int k0 = 0; k0 < 256; k0 += 64) {
        __syncthreads();
#pragma unroll
        for (int i = 0; i < 4; ++i) {
            int row = srow + i * 32;
            *(short8*)&As[row][soct * 8] =
                *(const short8*)&wT[((j0 + row) << 8) + k0 + soct * 8];
            *(short8*)&Bs[row][soct * 8] =
                *(const short8*)&xT[(((b << 12) + n0 + row) << 8) + k0 + soct * 8];
        }
        __syncthreads();
#pragma unroll
        for (int h = 0; h < 2; ++h) {
            short8 af[4], bfv[4];
#pragma unroll
            for (int mt = 0; mt < 4; ++mt)
                af[mt] = *(const short8*)&As[wr * 64 + mt * 16 + lm][h * 32 + lk];
#pragma unroll
            for (int nt = 0; nt < 4; ++nt)
                bfv[nt] = *(const short8*)&Bs[wc * 64 + nt * 16 + lm][h * 32 + lk];
#pragma unroll
            for (int mt = 0; mt < 4; ++mt)
#pragma unroll
                for (int nt = 0; nt < 4; ++nt)
                    acc[mt][nt] = MFMA16(af[mt], bfv[nt], acc[mt][nt]);
        }
    }
    const int jbase = wr * 64 + (l >> 4) * 4;
    const int jq = (y & 1) * 128;
    if (y < 4) {
        bf16* dst = (y < 2) ? qb : kb;
#pragma unroll
        for (int mt = 0; mt < 4; ++mt)
#pragma unroll
            for (int nt = 0; nt < 4; ++nt) {
                int n = n0 + wc * 64 + nt * 16 + lm;
#pragma unroll
                for (int r = 0; r < 4; ++r)
                    dst[(((b << 8) + jq + jbase + mt * 16 + r) << 12) + n] =
                        f2b(acc[mt][nt][r]);
            }
        __syncthreads();
        float* red = (float*)&As[0][0];
#pragma unroll
        for (int mt = 0; mt < 4; ++mt)
#pragma unroll
            for (int r = 0; r < 4; ++r) {
                float s = 0.f;
#pragma unroll
                for (int nt = 0; nt < 4; ++nt) {
                    float v = acc[mt][nt][r];
                    s = fmaf(v, v, s);
                }
                red[(jbase + mt * 16 + r) * 32 + wc * 16 + lm] = s;
            }
        __syncthreads();
        if (tid < 128) {
            float s = 0.f;
#pragma unroll
            for (int i = 0; i < 32; ++i)
                s += red[tid * 32 + ((i + tid) & 31)];
            float* dsts = (y < 2) ? qss : kss;
            atomicAdd(&dsts[(b << 8) + jq + tid], s);
        }
    } else {
#pragma unroll
        for (int mt = 0; mt < 4; ++mt)
#pragma unroll
            for (int nt = 0; nt < 4; ++nt) {
                int n = n0 + wc * 64 + nt * 16 + lm;
                short4v pv;
#pragma unroll
                for (int r = 0; r < 4; ++r) {
                    float vf = acc[mt][nt][r];
                    vbb[(((b << 8) + jq + jbase + mt * 16 + r) << 12) + n] = f2b(vf);
                    pv[r] = f2s(vf);
                }
                *(short4v*)&((short*)vT)[(((long)(b << 12) + n) << 8) +
                                         jq + jbase + mt * 16] = pv;
            }
    }
}

// ---------------------------------------------------------------------------
// K_qkdw (node 3): id<64 -> fused QK^T+softmax; id>=64 -> dwconv+BN+GELU+T.
// ---------------------------------------------------------------------------
__global__ __launch_bounds__(256) void k_qkdw(const bf16* __restrict__ qb,
                                              const bf16* __restrict__ kb,
                                              const float* __restrict__ qss,
                                              const float* __restrict__ kss,
                                              const bf16* __restrict__ vbb,
                                              const float* __restrict__ prm,
                                              float* __restrict__ attn,
                                              bf16* __restrict__ convT) {
    __shared__ __align__(16) char smem[38368];
    const int id = blockIdx.x;
    const int tid = threadIdx.x;
    if (id < 64) {
        float (*AS)[32] = (float(*)[32])smem;
        const int h = id & 7, b = id >> 3;
        const int wid = tid >> 6, l = tid & 63;
        const int lm = l & 15, lk = (l >> 4) * 8;
        floatx4 acc[2][2];
#pragma unroll
        for (int i = 0; i < 2; ++i)
#pragma unroll
            for (int j = 0; j < 2; ++j) acc[i][j] = (floatx4){0.f, 0.f, 0.f, 0.f};
        const int cbase = (b << 8) + h * 32;
        for (int it = 0; it < 32; ++it) {
            int n = wid * 1024 + it * 32 + lk;
            short8 a0 = *(const short8*)&qb[((cbase + lm) << 12) + n];
            short8 a1 = *(const short8*)&qb[((cbase + 16 + lm) << 12) + n];
            short8 b0 = *(const short8*)&kb[((cbase + lm) << 12) + n];
            short8 b1 = *(const short8*)&kb[((cbase + 16 + lm) << 12) + n];
            acc[0][0] = MFMA16(a0, b0, acc[0][0]);
            acc[0][1] = MFMA16(a0, b1, acc[0][1]);
            acc[1][0] = MFMA16(a1, b0, acc[1][0]);
            acc[1][1] = MFMA16(a1, b1, acc[1][1]);
        }
        for (int i = tid; i < 1024; i += 256) ((float*)AS)[i] = 0.f;
        __syncthreads();
#pragma unroll
        for (int mt = 0; mt < 2; ++mt)
#pragma unroll
            for (int nt = 0; nt < 2; ++nt)
#pragma unroll
                for (int r = 0; r < 4; ++r)
                    atomicAdd(&AS[mt * 16 + (l >> 4) * 4 + r][nt * 16 + lm],
                              acc[mt][nt][r]);
        __syncthreads();
        if (tid < 32) {
            const int c = tid;
            float qsc = rsqrtf(fmaxf(qss[cbase + c], 1e-12f)) * prm[P_TEMP + h];
            float row[32];
            float m = -1e30f;
#pragma unroll
            for (int d = 0; d < 32; ++d) {
                row[d] = AS[c][d] * qsc * rsqrtf(fmaxf(kss[cbase + d], 1e-12f));
                m = fmaxf(m, row[d]);
            }
            float s = 0.f;
#pragma unroll
            for (int d = 0; d < 32; ++d) {
                row[d] = __expf(row[d] - m);
                s += row[d];
            }
            float inv = 1.0f / s;
            float* dst = attn + ((b * 8 + h) << 10) + c * 32;
#pragma unroll
            for (int d = 0; d < 32; ++d) dst[d] = row[d] * inv;
        }
    } else {
        float (*S)[18][66] = (float(*)[18][66])smem;
        float (*Wl)[11] = (float(*)[11])(smem + 38016);
        const int id2 = id - 64;
        const int y0 = (id2 & 3) * 16, c0 = ((id2 >> 2) & 31) * 8, b = id2 >> 7;
        if (tid < 144) {
            int ch = tid / 18, r = tid - ch * 18;
            int gy = y0 + r - 1;
            float* drow = &S[ch][r][0];
            if (gy < 0 || gy > 63) {
                for (int i = 0; i < 66; ++i) drow[i] = 0.f;
            } else {
                const short* src = (const short*)vbb +
                                   ((((b << 8) + c0 + ch) << 12) + gy * 64);
                drow[0] = 0.f;
                drow[65] = 0.f;
#pragma unroll
                for (int g = 0; g < 8; ++g) {
                    short8 p = *(const short8*)(src + g * 8);
#pragma unroll
                    for (int u = 0; u < 8; ++u) drow[1 + g * 8 + u] = s2f(p[u]);
                }
            }
        } else if (tid >= 248) {
            int ch = tid - 248;
            int c = c0 + ch;
            float scale = rsqrtf(prm[P_DWV + c] + 1e-3f) * prm[P_DWG + c];
#pragma unroll
            for (int e = 0; e < 9; ++e) Wl[ch][e] = prm[P_DWK + c * 9 + e] * scale;
            Wl[ch][10] = (prm[P_DWB + c] - prm[P_DWM + c]) * scale + prm[P_DWBT + c];
        }
        __syncthreads();
        const int row = tid >> 4, xl = tid & 15;
#pragma unroll
        for (int u = 0; u < 4; ++u) {
            int x = xl + u * 16;
            short8 o;
#pragma unroll
            for (int ch = 0; ch < 8; ++ch) {
                float acc = Wl[ch][10];
#pragma unroll
                for (int ky = 0; ky < 3; ++ky)
#pragma unroll
                    for (int kx = 0; kx < 3; ++kx)
                        acc = fmaf(S[ch][row + ky][x + kx], Wl[ch][ky * 3 + kx], acc);
                o[ch] = f2s(gelu_exact(acc));
            }
            *(short8*)&((short*)convT)[(((b << 12) + (y0 + row) * 64 + x) << 8) + c0] = o;
        }
    }
}

// ---------------------------------------------------------------------------
// K_attv_sm (node 4): id<1024 -> att = P @ v via MFMA;
// id>=1024 (512 blocks) -> spatial gate via MFMA + shfl reduce.
// ---------------------------------------------------------------------------
__global__ __launch_bounds__(256) void k_attv_sm(const float* __restrict__ attn,
                                                 const bf16* __restrict__ vT,
                                                 const bf16* __restrict__ convT,
                                                 const float* __restrict__ prm,
                                                 bf16* __restrict__ attT,
                                                 float* __restrict__ gap,
                                                 float* __restrict__ sigsm) {
    __shared__ __align__(16) char smem[20608];
    const int id = blockIdx.x;
    const int tid = threadIdx.x;
    if (id < 1024) {
        float (*P)[32] = (float(*)[32])smem;             // 4 KB
        short (*AT)[32] = (short(*)[32])(smem + 4096);   // 16 KB [256][32]
        float* gacc = (float*)(smem + 4096 + 16384);     // 128 B
        const int nq = id & 15, h = (id >> 4) & 7, b = id >> 7;
        for (int i = tid; i < 1024; i += 256)
            ((float*)P)[i] = attn[((b * 8 + h) << 10) + i];
        if (tid < 32) gacc[tid] = 0.f;
        __syncthreads();
        const int w = tid >> 6, l = tid & 63;
        const int lm = l & 15, lk = (l >> 4) * 8;
        short8 bfr[2];
#pragma unroll
        for (int ct = 0; ct < 2; ++ct) {
            floatx4 p0 = *(const floatx4*)&P[ct * 16 + lm][lk];
            floatx4 p1 = *(const floatx4*)&P[ct * 16 + lm][lk + 4];
#pragma unroll
            for (int u = 0; u < 4; ++u) {
                bfr[ct][u] = f2s(p0[u]);
                bfr[ct][4 + u] = f2s(p1[u]);
            }
        }
        const floatx4 zero = {0.f, 0.f, 0.f, 0.f};
        const short* vTs = (const short*)vT;
#pragma unroll
        for (int t = 0; t < 4; ++t) {
            int nl = w * 64 + t * 16;
            int n0 = nq * 256 + nl;
            short8 afr = *(const short8*)&vTs[(((long)(b << 12) + n0 + lm) << 8) +
                                              h * 32 + lk];
            floatx4 d0 = MFMA16(afr, bfr[0], zero);
            floatx4 d1 = MFMA16(afr, bfr[1], zero);
            int rowb = nl + (l >> 4) * 4;
            float s0 = 0.f, s1 = 0.f;
#pragma unroll
            for (int r = 0; r < 4; ++r) {
                AT[rowb + r][lm] = f2s(d0[r]);
                AT[rowb + r][16 + lm] = f2s(d1[r]);
                s0 += d0[r];
                s1 += d1[r];
            }
            atomicAdd(&gacc[lm], s0);
            atomicAdd(&gacc[16 + lm], s1);
        }
        __syncthreads();
        const long gb = ((long)(b << 12) + nq * 256) << 8;
#pragma unroll
        for (int q = 0; q < 4; ++q) {
            int s = tid + q * 256;
            int row = s >> 2, grp = s & 3;
            *(short8*)&((short*)attT)[gb + ((long)row << 8) + h * 32 + grp * 8] =
                *(const short8*)&AT[row][grp * 8];
        }
        if (tid < 32) atomicAdd(&gap[(b << 8) + h * 32 + tid], gacc[tid]);
    } else {
        // ----- spatial gate via MFMA -----
        float (*W1s)[17] = (float(*)[17])smem;           // 256*17*4 = 17408 B
        const int id2 = id - 1024;                       // 0..511
        const int nx = id2 & 63, b = id2 >> 6;
        for (int i = tid; i < 4096; i += 256) W1s[i >> 4][i & 15] = prm[P_SIW1 + i];
        __syncthreads();
        const int w = tid >> 6, l = tid & 63;
        const int lm = l & 15, lk = (l >> 4) * 8;
        const int n0 = nx * 64 + w * 16;
        floatx4 acc = {0.f, 0.f, 0.f, 0.f};
        const short* cs = (const short*)convT;
#pragma unroll
        for (int ks = 0; ks < 8; ++ks) {
            int k0 = ks * 32;
            short8 afr = *(const short8*)&cs[(((long)(b << 12) + n0 + lm) << 8) +
                                             k0 + lk];
            short8 bfr;
#pragma unroll
            for (int i = 0; i < 8; ++i) bfr[i] = f2s(W1s[k0 + lk + i][lm]);
            acc = MFMA16(afr, bfr, acc);
        }
        const int o = lm;
        const float b1v = prm[P_SIB1 + o];
        const float scale = rsqrtf(prm[P_SIV + o] + 1e-3f) * prm[P_SIG + o];
        const float shift = prm[P_SIBT + o] - prm[P_SIM + o] * scale;
        const float w2v = prm[P_SIW2 + o];
        float part[4];
#pragma unroll
        for (int r = 0; r < 4; ++r) {
            float t = (acc[r] + b1v) * scale + shift;
            part[r] = gelu_exact(t) * w2v;
        }
#pragma unroll
        for (int off = 1; off < 16; off <<= 1)
#pragma unroll
            for (int r = 0; r < 4; ++r)
                part[r] += __shfl_xor(part[r], off, 64);
        if (lm == 0) {
            int nrow = n0 + (l >> 4) * 4;
            float b2 = prm[P_SIB2];
#pragma unroll
            for (int r = 0; r < 4; ++r)
                sigsm[(b << 12) + nrow + r] = sigmoidf_(b2 + part[r]);
        }
    }
}

// ---------------------------------------------------------------------------
// K9 (node 5): final projection (MFMA), 128x128 tile; inline channel gate.
// ---------------------------------------------------------------------------
__global__ __launch_bounds__(256) void k_proj_m3(const bf16* __restrict__ attT,
                                                 const bf16* __restrict__ convT,
                                                 const float* __restrict__ sigsm,
                                                 const float* __restrict__ gap,
                                                 const bf16* __restrict__ wpT,
                                                 const float* __restrict__ prm,
                                                 const unsigned* __restrict__ flag,
                                                 void* __restrict__ out) {
    __shared__ short As[128][72];
    __shared__ short Bs[128][72];
    __shared__ float scs[256];
    const bool isbf = (*flag != 0u);
    const int id = blockIdx.x;                 // 512 = 8 * 64
    const int swz = (id & 7) * 64 + (id >> 3);
    const int j0 = (swz & 1) * 128;
    const int rest = swz >> 1;
    const int n0 = (rest & 31) * 128;
    const int b = rest >> 5;
    const int tid = threadIdx.x;
    const int wid = tid >> 6, l = tid & 63;
    const int wr = wid >> 1, wc = wid & 1;
    const int lm = l & 15, lk = (l >> 4) * 8;
    const int srow = tid >> 3, soct = tid & 7;

    {
        float* gl = (float*)&As[0][0];
        float* rd = gl + 256;
        float* t1 = rd + 256;
        gl[tid] = gap[(b << 8) + tid] * (1.0f / 4096.0f);
        __syncthreads();
        const int o = tid >> 3, g = tid & 7;
        float s1 = 0.f;
#pragma unroll
        for (int i = 0; i < 32; ++i) {
            int c = g * 32 + i;
            s1 = fmaf(gl[c], prm[P_CIW1 + c * 32 + o], s1);
        }
        rd[o * 8 + g] = s1;
        __syncthreads();
        if (tid < 32) {
            float s = prm[P_CIB1 + tid];
#pragma unroll
            for (int g2 = 0; g2 < 8; ++g2) s += rd[tid * 8 + g2];
            s = (s - prm[P_CIM + tid]) * rsqrtf(prm[P_CIV + tid] + 1e-3f) *
                    prm[P_CIG + tid] + prm[P_CIBT + tid];
            t1[tid] = gelu_exact(s);
        }
        __syncthreads();
        float s = prm[P_CIB2 + tid];
#pragma unroll
        for (int o2 = 0; o2 < 32; ++o2)
            s = fmaf(t1[o2], prm[P_CIW2 + o2 * 256 + tid], s);
        scs[tid] = sigmoidf_(s);
    }

    floatx4 acc[4][4];
#pragma unroll
    for (int i = 0; i < 4; ++i)
#pragma unroll
        for (int j = 0; j < 4; ++j) acc[i][j] = (floatx4){0.f, 0.f, 0.f, 0.f};

    for (int k0 = 0; k0 < 256; k0 += 64) {
        __syncthreads();
#pragma unroll
        for (int i = 0; i < 4; ++i) {
            int row = srow + i * 32;
            *(short8*)&As[row][soct * 8] =
                *(const short8*)&wpT[((j0 + row) << 8) + k0 + soct * 8];
            int rbase = (((b << 12) + n0 + row) << 8) + k0 + soct * 8;
            short8 pa = *(const short8*)&attT[rbase];
            short8 pc = *(const short8*)&convT[rbase];
            float sv = sigsm[(b << 12) + n0 + row];
            short8 pz;
#pragma unroll
            for (int u = 0; u < 8; ++u)
                pz[u] = f2s(s2f(pa[u]) * sv + s2f(pc[u]) * scs[k0 + soct * 8 + u]);
            *(short8*)&Bs[row][soct * 8] = pz;
        }
        __syncthreads();
#pragma unroll
        for (int h = 0; h < 2; ++h) {
            short8 af[4], bfv[4];
#pragma unroll
            for (int mt = 0; mt < 4; ++mt)
                af[mt] = *(const short8*)&As[wr * 64 + mt * 16 + lm][h * 32 + lk];
#pragma unroll
            for (int nt = 0; nt < 4; ++nt)
                bfv[nt] = *(const short8*)&Bs[wc * 64 + nt * 16 + lm][h * 32 + lk];
#pragma unroll
            for (int mt = 0; mt < 4; ++mt)
#pragma unroll
                for (int nt = 0; nt < 4; ++nt)
                    acc[mt][nt] = MFMA16(af[mt], bfv[nt], acc[mt][nt]);
        }
    }
    const int jbase = j0 + wr * 64 + (l >> 4) * 4;
#pragma unroll
    for (int mt = 0; mt < 4; ++mt) {
        float bp[4];
#pragma unroll
        for (int r = 0; r < 4; ++r) bp[r] = prm[P_BPROJ + jbase + mt * 16 + r];
#pragma unroll
        for (int nt = 0; nt < 4; ++nt) {
            int n = n0 + wc * 64 + nt * 16 + lm;
#pragma unroll
            for (int r = 0; r < 4; ++r) {
                int idx = (((b << 8) + jbase + mt * 16 + r) << 12) + n;
                float val = acc[mt][nt][r] + bp[r];
                if (isbf) ((bf16*)out)[idx] = f2b(val);
                else ((float*)out)[idx] = val;
            }
        }
    }
}

// ---------------------------------------------------------------------------
extern "C" void kernel_launch(void* const* d_in, const int* in_sizes, int n_in,
                              void* d_out, int out_size, void* d_ws, size_t ws_size,
                              hipStream_t stream) {
    char* ws = (char*)d_ws;
    bf16*  vbb    = (bf16*) (ws);
    bf16*  xT     = (bf16*) (ws + 33554432);
    bf16*  attT   = (bf16*) (ws + 33554432);   // alias xT (dead after qkv)
    bf16*  qb     = (bf16*) (ws + 50331648);
    bf16*  kb     = (bf16*) (ws + 67108864);
    bf16*  wqkvT  = (bf16*) (ws + 83886080);
    bf16*  wprojT = (bf16*) (ws + 84279296);
    float* attn   = (float*)(ws + 84410368);
    float* qss    = (float*)(ws + 85721088);   // qss|kss|gap contiguous 24576B
    float* kss    = (float*)(ws + 85729280);
    float* gap    = (float*)(ws + 85737472);
    float* sigsm  = (float*)(ws + 85753856);
    float* prm    = (float*)(ws + 85884928);
    unsigned* flag = (unsigned*)(ws + 85985280);
    bf16*  convT  = (bf16*) (ws + 100663296);  // 96M..112M
    bf16*  vT     = (bf16*) (ws + 117440512);  // 112M..128M

    CvtArgs a;
    const int map_src[24] = {3, 4, 5, 6, 7, 8, 9, 10, 11, 12, 13, 14, 15, 16, 17,
                             18, 19, 20, 21, 22, 23, 24, 25, 26};
    const int map_dst[24] = {P_BPROJ, P_DWK, P_DWB, P_DWG, P_DWBT, P_DWM, P_DWV,
                             P_CIG, P_CIBT, P_CIM, P_CIV, P_SIG, P_SIBT, P_SIM, P_SIV,
                             P_CIW1, P_CIB1, P_CIW2, P_CIB2, P_SIW1, P_SIB1, P_SIW2,
                             P_SIB2, P_TEMP};
    for (int i = 0; i < 24; ++i) {
        a.src[i] = d_in[map_src[i]];
        a.dst[i] = map_dst[i];
        a.cnt[i] = in_sizes[map_src[i]];
    }

    k_prept<<<2137, 256, 0, stream>>>(a, d_in[0], d_in[1], d_in[2],
                                      xT, wqkvT, wprojT, prm, flag, qss);
    k_qkv_m3<<<1536, 256, 0, stream>>>(xT, wqkvT, qb, kb, vbb, vT, qss, kss);
    k_qkdw<<<1088, 256, 0, stream>>>(qb, kb, qss, kss, vbb, prm, attn, convT);
    k_attv_sm<<<1536, 256, 0, stream>>>(attn, vT, convT, prm, attT, gap, sigsm);
    k_proj_m3<<<512, 256, 0, stream>>>(attT, convT, sigsm, gap,
                                       wprojT, prm, flag, d_out);
}